// Round 1
// baseline (1514.510 us; speedup 1.0000x reference)
//
#include <hip/hip_runtime.h>
#include <math.h>

#define PTS   8
#define TT    8
#define HID   256
#define OUTD  520
#define NBINS 32
#define XSTR  17
#define BN_EPS 1e-5f
#define ROWS  16
#define H2STR 260   // padded stride so tail-GEMM LDS reads spread banks

// workspace float offsets
#define WS_SUM0   0
#define WS_SS0    8
#define WS_SC0   16
#define WS_BI0   24
#define WS_SUM1  32
#define WS_SS1   288
#define WS_SC1   544
#define WS_BI1   800
#define WS_SUM2  1056
#define WS_SS2   1312
#define WS_SC2   1568
#define WS_BI2   1824
#define WS_TOTAL 2080

__global__ __launch_bounds__(256) void k_stats0(const float* __restrict__ x,
                                                float* __restrict__ ws, int B) {
  float s[PTS], ss[PTS];
  #pragma unroll
  for (int c = 0; c < PTS; c++) { s[c] = 0.f; ss[c] = 0.f; }
  for (int r = blockIdx.x * blockDim.x + threadIdx.x; r < B; r += gridDim.x * blockDim.x) {
    const float* xr = x + (size_t)r * XSTR;
    #pragma unroll
    for (int c = 0; c < PTS; c++) { float v = xr[c]; s[c] += v; ss[c] += v * v; }
  }
  #pragma unroll
  for (int c = 0; c < PTS; c++) {
    float a = s[c], b = ss[c];
    #pragma unroll
    for (int off = 32; off > 0; off >>= 1) {
      a += __shfl_down(a, off, 64);
      b += __shfl_down(b, off, 64);
    }
    if ((threadIdx.x & 63) == 0) {
      atomicAdd(&ws[WS_SUM0 + c], a);
      atomicAdd(&ws[WS_SS0 + c], b);
    }
  }
}

__global__ void k_finalize(float* __restrict__ ws, const float* __restrict__ g,
                           const float* __restrict__ b, int sum_off, int ss_off,
                           int sc_off, int bi_off, int n, float invB) {
  int i = blockIdx.x * blockDim.x + threadIdx.x;
  if (i < n) {
    float m  = ws[sum_off + i] * invB;
    float v  = ws[ss_off + i] * invB - m * m;
    float sc = g[i] * rsqrtf(v + BN_EPS);
    ws[sc_off + i] = sc;
    ws[bi_off + i] = b[i] - m * sc;
  }
}

__global__ __launch_bounds__(256) void k_stats1(const float* __restrict__ x,
                                                const float* __restrict__ w1,
                                                float* __restrict__ ws, int B) {
  __shared__ float a1[ROWS][PTS];
  __shared__ float red[2][4][HID];
  const float* sc0 = ws + WS_SC0; const float* bi0 = ws + WS_BI0;
  const int t = threadIdx.x, q = t >> 6, c4 = (t & 63) << 2;
  float s[4] = {0, 0, 0, 0}, ssq[4] = {0, 0, 0, 0};
  const int ntiles = B / ROWS;
  for (int tile = blockIdx.x; tile < ntiles; tile += gridDim.x) {
    const int r0 = tile * ROWS;
    __syncthreads();
    if (t < ROWS * PTS) {
      int r = t >> 3, c = t & 7;
      a1[r][c] = x[(size_t)(r0 + r) * XSTR + c] * sc0[c] + bi0[c];
    }
    __syncthreads();
    float acc[4][4];
    #pragma unroll
    for (int i = 0; i < 4; i++) { acc[i][0]=0;acc[i][1]=0;acc[i][2]=0;acc[i][3]=0; }
    #pragma unroll
    for (int k = 0; k < PTS; k++) {
      float4 wv = *(const float4*)&w1[k * HID + c4];
      #pragma unroll
      for (int i = 0; i < 4; i++) {
        float av = a1[q * 4 + i][k];
        acc[i][0] += av * wv.x; acc[i][1] += av * wv.y;
        acc[i][2] += av * wv.z; acc[i][3] += av * wv.w;
      }
    }
    #pragma unroll
    for (int i = 0; i < 4; i++) {
      #pragma unroll
      for (int j = 0; j < 4; j++) { float v = acc[i][j]; s[j] += v; ssq[j] += v * v; }
    }
  }
  #pragma unroll
  for (int j = 0; j < 4; j++) { red[0][q][c4 + j] = s[j]; red[1][q][c4 + j] = ssq[j]; }
  __syncthreads();
  {
    float a = red[0][0][t] + red[0][1][t] + red[0][2][t] + red[0][3][t];
    float b = red[1][0][t] + red[1][1][t] + red[1][2][t] + red[1][3][t];
    atomicAdd(&ws[WS_SUM1 + t], a);
    atomicAdd(&ws[WS_SS1 + t], b);
  }
}

__global__ __launch_bounds__(256) void k_stats2(const float* __restrict__ x,
                                                const float* __restrict__ w1,
                                                const float* __restrict__ w2,
                                                float* __restrict__ ws, int B) {
  __shared__ float a1[ROWS][PTS];
  __shared__ __align__(16) float h1s[ROWS][HID];
  __shared__ float red[2][4][HID];
  const float* sc0 = ws + WS_SC0; const float* bi0 = ws + WS_BI0;
  const float* sc1 = ws + WS_SC1; const float* bi1 = ws + WS_BI1;
  const int t = threadIdx.x, q = t >> 6, c4 = (t & 63) << 2;
  float s[4] = {0, 0, 0, 0}, ssq[4] = {0, 0, 0, 0};
  const int ntiles = B / ROWS;
  for (int tile = blockIdx.x; tile < ntiles; tile += gridDim.x) {
    const int r0 = tile * ROWS;
    __syncthreads();
    if (t < ROWS * PTS) {
      int r = t >> 3, c = t & 7;
      a1[r][c] = x[(size_t)(r0 + r) * XSTR + c] * sc0[c] + bi0[c];
    }
    __syncthreads();
    // h1 = relu(bn1(a1 @ w1))
    {
      float acc[4][4];
      #pragma unroll
      for (int i = 0; i < 4; i++) { acc[i][0]=0;acc[i][1]=0;acc[i][2]=0;acc[i][3]=0; }
      #pragma unroll
      for (int k = 0; k < PTS; k++) {
        float4 wv = *(const float4*)&w1[k * HID + c4];
        #pragma unroll
        for (int i = 0; i < 4; i++) {
          float av = a1[q * 4 + i][k];
          acc[i][0] += av * wv.x; acc[i][1] += av * wv.y;
          acc[i][2] += av * wv.z; acc[i][3] += av * wv.w;
        }
      }
      float4 s1v = *(const float4*)&sc1[c4];
      float4 b1v = *(const float4*)&bi1[c4];
      #pragma unroll
      for (int i = 0; i < 4; i++) {
        float4 hv;
        hv.x = fmaxf(acc[i][0] * s1v.x + b1v.x, 0.f);
        hv.y = fmaxf(acc[i][1] * s1v.y + b1v.y, 0.f);
        hv.z = fmaxf(acc[i][2] * s1v.z + b1v.z, 0.f);
        hv.w = fmaxf(acc[i][3] * s1v.w + b1v.w, 0.f);
        *(float4*)&h1s[q * 4 + i][c4] = hv;
      }
    }
    __syncthreads();
    // h2_pre = h1 @ w2 ; accumulate stats
    {
      float acc[4][4];
      #pragma unroll
      for (int i = 0; i < 4; i++) { acc[i][0]=0;acc[i][1]=0;acc[i][2]=0;acc[i][3]=0; }
      for (int k = 0; k < HID; k += 4) {
        float4 wa = *(const float4*)&w2[(size_t)(k + 0) * HID + c4];
        float4 wb = *(const float4*)&w2[(size_t)(k + 1) * HID + c4];
        float4 wc = *(const float4*)&w2[(size_t)(k + 2) * HID + c4];
        float4 wd = *(const float4*)&w2[(size_t)(k + 3) * HID + c4];
        #pragma unroll
        for (int i = 0; i < 4; i++) {
          float4 hv = *(const float4*)&h1s[q * 4 + i][k];
          acc[i][0] += hv.x * wa.x + hv.y * wb.x + hv.z * wc.x + hv.w * wd.x;
          acc[i][1] += hv.x * wa.y + hv.y * wb.y + hv.z * wc.y + hv.w * wd.y;
          acc[i][2] += hv.x * wa.z + hv.y * wb.z + hv.z * wc.z + hv.w * wd.z;
          acc[i][3] += hv.x * wa.w + hv.y * wb.w + hv.z * wc.w + hv.w * wd.w;
        }
      }
      #pragma unroll
      for (int i = 0; i < 4; i++) {
        #pragma unroll
        for (int j = 0; j < 4; j++) { float v = acc[i][j]; s[j] += v; ssq[j] += v * v; }
      }
    }
  }
  #pragma unroll
  for (int j = 0; j < 4; j++) { red[0][q][c4 + j] = s[j]; red[1][q][c4 + j] = ssq[j]; }
  __syncthreads();
  {
    float a = red[0][0][t] + red[0][1][t] + red[0][2][t] + red[0][3][t];
    float b = red[1][0][t] + red[1][1][t] + red[1][2][t] + red[1][3][t];
    atomicAdd(&ws[WS_SUM2 + t], a);
    atomicAdd(&ws[WS_SS2 + t], b);
  }
}

__global__ __launch_bounds__(256) void k_final(const float* __restrict__ x,
                                               const float* __restrict__ w1,
                                               const float* __restrict__ w2,
                                               const float* __restrict__ w3,
                                               const float* __restrict__ b3,
                                               const float* __restrict__ ws,
                                               float* __restrict__ out, int B) {
  __shared__ float a1[ROWS][PTS];
  __shared__ float xb[ROWS][TT];
  __shared__ float jacv[ROWS];
  __shared__ __align__(16) float h2s[ROWS][H2STR];
  __shared__ __align__(16) float buf[ROWS * OUTD];  // h1 lives in [0, ROWS*HID) early; Z later
  __shared__ float densl[ROWS][TT];

  const float* sc0 = ws + WS_SC0; const float* bi0 = ws + WS_BI0;
  const float* sc1 = ws + WS_SC1; const float* bi1 = ws + WS_BI1;
  const float* sc2 = ws + WS_SC2; const float* bi2 = ws + WS_BI2;

  const int t = threadIdx.x;
  const int q = t >> 6;
  const int c4 = (t & 63) << 2;
  const int r0 = blockIdx.x * ROWS;

  if (t < 128) {
    int r = t >> 3, c = t & 7;
    a1[r][c] = x[(size_t)(r0 + r) * XSTR + c] * sc0[c] + bi0[c];
  } else {
    int r = (t - 128) >> 3, c = (t - 128) & 7;
    xb[r][c] = fminf(x[(size_t)(r0 + r) * XSTR + PTS + c], 1.0f - 1e-6f);
  }
  if (t < ROWS) jacv[t] = x[(size_t)(r0 + t) * XSTR + 16];
  __syncthreads();

  // h1 = relu(bn1(a1 @ w1)) -> buf[r*HID + c]
  {
    float acc[4][4];
    #pragma unroll
    for (int i = 0; i < 4; i++) { acc[i][0]=0;acc[i][1]=0;acc[i][2]=0;acc[i][3]=0; }
    #pragma unroll
    for (int k = 0; k < PTS; k++) {
      float4 wv = *(const float4*)&w1[k * HID + c4];
      #pragma unroll
      for (int i = 0; i < 4; i++) {
        float av = a1[q * 4 + i][k];
        acc[i][0] += av * wv.x; acc[i][1] += av * wv.y;
        acc[i][2] += av * wv.z; acc[i][3] += av * wv.w;
      }
    }
    float4 s1v = *(const float4*)&sc1[c4];
    float4 b1v = *(const float4*)&bi1[c4];
    #pragma unroll
    for (int i = 0; i < 4; i++) {
      float4 hv;
      hv.x = fmaxf(acc[i][0] * s1v.x + b1v.x, 0.f);
      hv.y = fmaxf(acc[i][1] * s1v.y + b1v.y, 0.f);
      hv.z = fmaxf(acc[i][2] * s1v.z + b1v.z, 0.f);
      hv.w = fmaxf(acc[i][3] * s1v.w + b1v.w, 0.f);
      *(float4*)&buf[(q * 4 + i) * HID + c4] = hv;
    }
  }
  __syncthreads();

  // h2 = relu(bn2(h1 @ w2)) -> h2s
  {
    float acc[4][4];
    #pragma unroll
    for (int i = 0; i < 4; i++) { acc[i][0]=0;acc[i][1]=0;acc[i][2]=0;acc[i][3]=0; }
    for (int k = 0; k < HID; k += 4) {
      float4 wa = *(const float4*)&w2[(size_t)(k + 0) * HID + c4];
      float4 wb = *(const float4*)&w2[(size_t)(k + 1) * HID + c4];
      float4 wc = *(const float4*)&w2[(size_t)(k + 2) * HID + c4];
      float4 wd = *(const float4*)&w2[(size_t)(k + 3) * HID + c4];
      #pragma unroll
      for (int i = 0; i < 4; i++) {
        float4 hv = *(const float4*)&buf[(q * 4 + i) * HID + k];
        acc[i][0] += hv.x * wa.x + hv.y * wb.x + hv.z * wc.x + hv.w * wd.x;
        acc[i][1] += hv.x * wa.y + hv.y * wb.y + hv.z * wc.y + hv.w * wd.y;
        acc[i][2] += hv.x * wa.z + hv.y * wb.z + hv.z * wc.z + hv.w * wd.z;
        acc[i][3] += hv.x * wa.w + hv.y * wb.w + hv.z * wc.w + hv.w * wd.w;
      }
    }
    float4 s2v = *(const float4*)&sc2[c4];
    float4 b2v = *(const float4*)&bi2[c4];
    #pragma unroll
    for (int i = 0; i < 4; i++) {
      float4 hv;
      hv.x = fmaxf(acc[i][0] * s2v.x + b2v.x, 0.f);
      hv.y = fmaxf(acc[i][1] * s2v.y + b2v.y, 0.f);
      hv.z = fmaxf(acc[i][2] * s2v.z + b2v.z, 0.f);
      hv.w = fmaxf(acc[i][3] * s2v.w + b2v.w, 0.f);
      *(float4*)&h2s[q * 4 + i][c4] = hv;
    }
  }
  __syncthreads();

  // Z = h2 @ w3 + b3 -> buf[r*OUTD + c]  (h1 is dead, overwrite)
  #pragma unroll
  for (int chunk = 0; chunk < 2; chunk++) {
    const int co = chunk * 256 + c4;
    float acc[4][4];
    #pragma unroll
    for (int i = 0; i < 4; i++) { acc[i][0]=0;acc[i][1]=0;acc[i][2]=0;acc[i][3]=0; }
    for (int k = 0; k < HID; k += 4) {
      float4 wa = *(const float4*)&w3[(size_t)(k + 0) * OUTD + co];
      float4 wb = *(const float4*)&w3[(size_t)(k + 1) * OUTD + co];
      float4 wc = *(const float4*)&w3[(size_t)(k + 2) * OUTD + co];
      float4 wd = *(const float4*)&w3[(size_t)(k + 3) * OUTD + co];
      #pragma unroll
      for (int i = 0; i < 4; i++) {
        float4 hv = *(const float4*)&h2s[q * 4 + i][k];
        acc[i][0] += hv.x * wa.x + hv.y * wb.x + hv.z * wc.x + hv.w * wd.x;
        acc[i][1] += hv.x * wa.y + hv.y * wb.y + hv.z * wc.y + hv.w * wd.y;
        acc[i][2] += hv.x * wa.z + hv.y * wb.z + hv.z * wc.z + hv.w * wd.z;
        acc[i][3] += hv.x * wa.w + hv.y * wb.w + hv.z * wc.w + hv.w * wd.w;
      }
    }
    float4 b3v = *(const float4*)&b3[co];
    #pragma unroll
    for (int i = 0; i < 4; i++) {
      float4 zv;
      zv.x = acc[i][0] + b3v.x;
      zv.y = acc[i][1] + b3v.y;
      zv.z = acc[i][2] + b3v.z;
      zv.w = acc[i][3] + b3v.w;
      *(float4*)&buf[(q * 4 + i) * OUTD + co] = zv;
    }
  }
  // tail cols 512..519 (one scalar col per thread for t<128)
  if (t < 128) {
    int r = t >> 3, c = 512 + (t & 7);
    float acc = 0.f;
    for (int k = 0; k < HID; k++) acc += h2s[r][k] * w3[(size_t)k * OUTD + c];
    buf[r * OUTD + c] = acc + b3[c];
  }
  __syncthreads();

  // spline per (row, t)
  if (t < 128) {
    const int r = t >> 3, u = t & 7;
    float* zp = &buf[r * OUTD + u * (2 * NBINS + 1)];
    const float xB = xb[r][u];
    float v0 = __expf(zp[0]); zp[0] = v0;
    float Wn = 0.f, Vtot = 0.f, vprev = v0;
    #pragma unroll
    for (int i = 0; i < NBINS; i++) {
      float v1 = __expf(zp[i + 1]); zp[i + 1] = v1;
      float w  = __expf(zp[NBINS + 1 + i]); zp[NBINS + 1 + i] = w;
      Wn += w; Vtot += 0.5f * (vprev + v1) * w; vprev = v1;
    }
    const float xT = xB * Wn;
    float cs = 0.f, csj = 0.f, U = 0.f; int j = 0;
    #pragma unroll
    for (int i = 0; i < NBINS; i++) {
      float w = zp[NBINS + 1 + i];
      float bar = 0.5f * (zp[i] + zp[i + 1]) * w;
      cs += w;
      if (cs <= xT) { j = i + 1; csj = cs; U += bar; }
    }
    const float Vj = zp[j], Vj1 = zp[j + 1], Wj = zp[NBINS + 1 + j];
    const float alpha = (xT - csj) / Wj;
    const float dV = Vj1 - Vj;
    const float yB = ((0.5f * alpha * alpha * dV + alpha * Vj) * Wj + U) / Vtot;
    const float dens = (Vj + alpha * dV) * Wn / Vtot;
    out[(size_t)(r0 + r) * XSTR + PTS + u] = yB;
    densl[r][u] = dens;
    out[(size_t)(r0 + r) * XSTR + u] = x[(size_t)(r0 + r) * XSTR + u];  // xA copy
  }
  __syncthreads();
  if (t < ROWS) {
    float p = jacv[t];
    #pragma unroll
    for (int u = 0; u < TT; u++) p *= densl[t][u];
    out[(size_t)(r0 + t) * XSTR + 16] = p;
  }
}

extern "C" void kernel_launch(void* const* d_in, const int* in_sizes, int n_in,
                              void* d_out, int out_size, void* d_ws, size_t ws_size,
                              hipStream_t stream) {
  (void)n_in; (void)out_size; (void)ws_size;
  const float* x  = (const float*)d_in[0];
  const float* g0 = (const float*)d_in[1];
  const float* b0 = (const float*)d_in[2];
  const float* w1 = (const float*)d_in[3];
  const float* g1 = (const float*)d_in[4];
  const float* b1 = (const float*)d_in[5];
  const float* w2 = (const float*)d_in[6];
  const float* g2 = (const float*)d_in[7];
  const float* b2 = (const float*)d_in[8];
  const float* w3 = (const float*)d_in[9];
  const float* b3 = (const float*)d_in[10];
  float* out = (float*)d_out;
  float* ws  = (float*)d_ws;
  const int B = in_sizes[0] / XSTR;
  const float invB = 1.0f / (float)B;

  hipMemsetAsync(d_ws, 0, WS_TOTAL * sizeof(float), stream);
  k_stats0<<<256, 256, 0, stream>>>(x, ws, B);
  k_finalize<<<1, 64, 0, stream>>>(ws, g0, b0, WS_SUM0, WS_SS0, WS_SC0, WS_BI0, PTS, invB);
  k_stats1<<<1024, 256, 0, stream>>>(x, w1, ws, B);
  k_finalize<<<1, 256, 0, stream>>>(ws, g1, b1, WS_SUM1, WS_SS1, WS_SC1, WS_BI1, HID, invB);
  k_stats2<<<1024, 256, 0, stream>>>(x, w1, w2, ws, B);
  k_finalize<<<1, 256, 0, stream>>>(ws, g2, b2, WS_SUM2, WS_SS2, WS_SC2, WS_BI2, HID, invB);
  k_final<<<B / ROWS, 256, 0, stream>>>(x, w1, w2, w3, b3, ws, out, B);
}

// Round 2
// 752.582 us; speedup vs baseline: 2.0124x; 2.0124x over previous
//
#include <hip/hip_runtime.h>
#include <math.h>

#define PTS   8
#define HID   256
#define OUTD  520
#define NBINS 32
#define XSTR  17
#define BN_EPS 1e-5f

typedef short bfrag __attribute__((ext_vector_type(8)));   // 8 bf16 (4 VGPRs)
typedef float f32x4 __attribute__((ext_vector_type(4)));

union BF8 { bfrag v; ushort u[8]; };

__device__ __forceinline__ ushort f2bf(float f) {          // RNE float->bf16
  uint u = __float_as_uint(f);
  return (ushort)((u + 0x7FFFu + ((u >> 16) & 1u)) >> 16);
}

#define MFMA(a, b, c) __builtin_amdgcn_mfma_f32_16x16x32_bf16((a), (b), (c), 0, 0, 0)

// ---- workspace float offsets ----
#define WS_SUMX   0      // 8
#define WS_SXX    8      // 64 (8x8 second moment of xA)
#define WS_SC0    72     // 8
#define WS_BI0    80     // 8
#define WS_SC1    88     // 256
#define WS_B1F    344    // 256 (fused layer1 bias)
#define WS_SUM2   600    // 256
#define WS_SS2    856    // 256
#define WS_SC2    1112   // 256
#define WS_BI2    1368   // 256
#define WS_STATS_END 1624
#define WS_W1B    1632   // 8192 ushorts (16 ntile x 64 lane x 8)
#define WS_W2B    5728   // 65536 ushorts (16 x 8 x 64 x 8)
#define WS_W3B    38496  // 135168 ushorts (33 x 8 x 64 x 8)

// ================= stats0: first+second moments of xA =================
__global__ __launch_bounds__(256) void k_stats0(const float* __restrict__ x,
                                                float* __restrict__ ws, int B) {
  float sx[8];
  float sxx[8][8];
  #pragma unroll
  for (int i = 0; i < 8; i++) {
    sx[i] = 0.f;
    #pragma unroll
    for (int j = 0; j < 8; j++) sxx[i][j] = 0.f;
  }
  for (int r = blockIdx.x * blockDim.x + threadIdx.x; r < B; r += gridDim.x * blockDim.x) {
    const float* xr = x + (size_t)r * XSTR;
    float v[8];
    #pragma unroll
    for (int c = 0; c < 8; c++) v[c] = xr[c];
    #pragma unroll
    for (int i = 0; i < 8; i++) {
      sx[i] += v[i];
      #pragma unroll
      for (int j = 0; j < 8; j++) sxx[i][j] += v[i] * v[j];
    }
  }
  #pragma unroll
  for (int i = 0; i < 8; i++) {
    float a = sx[i];
    a += __shfl_xor(a, 1);  a += __shfl_xor(a, 2);  a += __shfl_xor(a, 4);
    a += __shfl_xor(a, 8);  a += __shfl_xor(a, 16); a += __shfl_xor(a, 32);
    if ((threadIdx.x & 63) == 0) atomicAdd(&ws[WS_SUMX + i], a);
  }
  #pragma unroll
  for (int i = 0; i < 8; i++) {
    #pragma unroll
    for (int j = 0; j < 8; j++) {
      float a = sxx[i][j];
      a += __shfl_xor(a, 1);  a += __shfl_xor(a, 2);  a += __shfl_xor(a, 4);
      a += __shfl_xor(a, 8);  a += __shfl_xor(a, 16); a += __shfl_xor(a, 32);
      if ((threadIdx.x & 63) == 0) atomicAdd(&ws[WS_SXX + i * 8 + j], a);
    }
  }
}

// ====== fin0: bn0 params + ANALYTIC bn1 stats (var = w' Cov w) + fused bias ======
__global__ void k_fin0(const float* __restrict__ w1, const float* __restrict__ g0,
                       const float* __restrict__ b0, const float* __restrict__ g1,
                       const float* __restrict__ b1, float* __restrict__ ws, float invB) {
  __shared__ float smx[8], ssc[8], sbi[8], sma[8], scov[8][8];
  const int t = threadIdx.x;
  if (t < 8) {
    float mx  = ws[WS_SUMX + t] * invB;
    float ex2 = ws[WS_SXX + t * 8 + t] * invB;
    float var = ex2 - mx * mx;
    float sc  = g0[t] * rsqrtf(var + BN_EPS);
    float bi  = b0[t] - mx * sc;
    ws[WS_SC0 + t] = sc; ws[WS_BI0 + t] = bi;
    smx[t] = mx; ssc[t] = sc; sbi[t] = bi; sma[t] = sc * mx + bi;
  }
  __syncthreads();
  if (t < 64) {
    int i = t >> 3, j = t & 7;
    float e = ssc[i] * ssc[j] * (ws[WS_SXX + i * 8 + j] * invB)
            + ssc[i] * smx[i] * sbi[j] + sbi[i] * ssc[j] * smx[j] + sbi[i] * sbi[j];
    scov[i][j] = e - sma[i] * sma[j];
  }
  __syncthreads();
  float wc[8];
  float m1 = 0.f, bvec = 0.f;
  #pragma unroll
  for (int k = 0; k < 8; k++) {
    wc[k] = w1[k * HID + t];
    m1   += sma[k] * wc[k];
    bvec += sbi[k] * wc[k];
  }
  float var1 = 0.f;
  #pragma unroll
  for (int i = 0; i < 8; i++)
    #pragma unroll
    for (int j = 0; j < 8; j++) var1 += wc[i] * wc[j] * scov[i][j];
  float sc1 = g1[t] * rsqrtf(var1 + BN_EPS);
  float bi1 = b1[t] - m1 * sc1;
  ws[WS_SC1 + t] = sc1;
  ws[WS_B1F + t] = bvec * sc1 + bi1;
}

// ================= weight fragment packing (bf16) =================
__global__ void k_pack_w1(const float* __restrict__ w1, float* __restrict__ ws) {
  int idx = blockIdx.x * blockDim.x + threadIdx.x;
  if (idx >= 16 * 64 * 8) return;
  int i = idx & 7, l = (idx >> 3) & 63, n = idx >> 9;
  int k = (l >> 4) * 8 + i, col = n * 16 + (l & 15);
  float v = (k < 8) ? ws[WS_SC0 + k] * w1[k * HID + col] * ws[WS_SC1 + col] : 0.f;
  ((ushort*)(ws + WS_W1B))[idx] = f2bf(v);
}

__global__ void k_pack_w2(const float* __restrict__ w2, float* __restrict__ ws) {
  int idx = blockIdx.x * blockDim.x + threadIdx.x;
  if (idx >= 16 * 8 * 64 * 8) return;
  int i = idx & 7, l = (idx >> 3) & 63, s = (idx >> 9) & 7, n = idx >> 12;
  int k = s * 32 + (l >> 4) * 8 + i, col = n * 16 + (l & 15);
  ((ushort*)(ws + WS_W2B))[idx] = f2bf(w2[k * HID + col]);
}

__global__ void k_pack_w3(const float* __restrict__ w3, float* __restrict__ ws) {
  int idx = blockIdx.x * blockDim.x + threadIdx.x;
  if (idx >= 33 * 8 * 64 * 8) return;
  int i = idx & 7, l = (idx >> 3) & 63, s = (idx >> 9) & 7, n = idx >> 12;
  int k = s * 32 + (l >> 4) * 8 + i, col = n * 16 + (l & 15);
  float v = (col < OUTD) ? w3[(size_t)k * OUTD + col] : 0.f;
  ((ushort*)(ws + WS_W3B))[idx] = f2bf(v);
}

// ================= stats2: bn2 moments via MFMA h2_pre =================
__global__ __launch_bounds__(512) void k_stats2(const float* __restrict__ x,
                                                float* __restrict__ ws, int B) {
  __shared__ ushort hb[2 * 16 * 256];
  const ushort* w1b = (const ushort*)(ws + WS_W1B);
  const ushort* w2b = (const ushort*)(ws + WS_W2B);
  const int t = threadIdx.x, wv = t >> 6, l = t & 63, lr = l & 15, g = l >> 4;
  float sacc[2] = {0.f, 0.f}, ssacc[2] = {0.f, 0.f};
  const int ntiles = B / 32;
  for (int tile = blockIdx.x; tile < ntiles; tile += gridDim.x) {
    const int r0 = tile * 32;
    BF8 ax[2];
    #pragma unroll
    for (int mt = 0; mt < 2; mt++) {
      if (l < 16) {
        const float* xr = x + (size_t)(r0 + mt * 16 + lr) * XSTR;
        #pragma unroll
        for (int i2 = 0; i2 < 8; i2++) ax[mt].u[i2] = f2bf(xr[i2]);
      } else {
        #pragma unroll
        for (int i2 = 0; i2 < 8; i2++) ax[mt].u[i2] = 0;
      }
    }
    // layer1 -> h1 (LDS, swizzled)
    #pragma unroll
    for (int j = 0; j < 2; j++) {
      int n = wv * 2 + j;
      BF8 bw; bw.v = *(const bfrag*)(w1b + ((size_t)n * 64 + l) * 8);
      int col = n * 16 + lr;
      float b1fv = ws[WS_B1F + col];
      f32x4 cini = {b1fv, b1fv, b1fv, b1fv};
      #pragma unroll
      for (int mt = 0; mt < 2; mt++) {
        f32x4 d = MFMA(ax[mt].v, bw.v, cini);
        #pragma unroll
        for (int r = 0; r < 4; r++) {
          int row = 4 * g + r;
          float h = fmaxf(d[r], 0.f);
          int byte = ((mt * 16 + row) * 256) * 2 + ((col * 2) ^ ((row & 7) << 4));
          *(ushort*)((char*)hb + byte) = f2bf(h);
        }
      }
    }
    __syncthreads();
    BF8 a2[2][8];
    #pragma unroll
    for (int mt = 0; mt < 2; mt++)
      #pragma unroll
      for (int s = 0; s < 8; s++) {
        int byte = ((mt * 16 + lr) * 256) * 2 + ((s * 64 + g * 16) ^ ((lr & 7) << 4));
        a2[mt][s].v = *(const bfrag*)((const char*)hb + byte);
      }
    __syncthreads();
    // layer2 h2_pre, accumulate moments
    #pragma unroll
    for (int j = 0; j < 2; j++) {
      int n = wv * 2 + j;
      f32x4 acc0 = {0.f, 0.f, 0.f, 0.f}, acc1 = {0.f, 0.f, 0.f, 0.f};
      #pragma unroll
      for (int s = 0; s < 8; s++) {
        BF8 bw; bw.v = *(const bfrag*)(w2b + (((size_t)n * 8 + s) * 64 + l) * 8);
        acc0 = MFMA(a2[0][s].v, bw.v, acc0);
        acc1 = MFMA(a2[1][s].v, bw.v, acc1);
      }
      float ls = 0.f, lss = 0.f;
      #pragma unroll
      for (int r = 0; r < 4; r++) {
        ls  += acc0[r] + acc1[r];
        lss += acc0[r] * acc0[r] + acc1[r] * acc1[r];
      }
      sacc[j] += ls; ssacc[j] += lss;
    }
  }
  #pragma unroll
  for (int j = 0; j < 2; j++) {
    float a = sacc[j], b = ssacc[j];
    a += __shfl_xor(a, 16); a += __shfl_xor(a, 32);
    b += __shfl_xor(b, 16); b += __shfl_xor(b, 32);
    if (g == 0) {
      int col = (wv * 2 + j) * 16 + lr;
      atomicAdd(&ws[WS_SUM2 + col], a);
      atomicAdd(&ws[WS_SS2 + col], b);
    }
  }
}

__global__ void k_fin2(const float* __restrict__ g2, const float* __restrict__ b2,
                       float* __restrict__ ws, float invB) {
  int t = threadIdx.x;
  float m   = ws[WS_SUM2 + t] * invB;
  float var = ws[WS_SS2 + t] * invB - m * m;
  float sc  = g2[t] * rsqrtf(var + BN_EPS);
  ws[WS_SC2 + t] = sc;
  ws[WS_BI2 + t] = b2[t] - m * sc;
}

// ================= final: full fused pipeline =================
__global__ __launch_bounds__(512) void k_final(const float* __restrict__ x,
                                               const float* __restrict__ b3,
                                               const float* __restrict__ ws,
                                               float* __restrict__ out, int B) {
  __shared__ union {
    ushort hb[2 * 16 * 256];   // 16 KB: h1 then h2 staging (swizzled)
    float  Z[32 * 528];        // 66 KB: fp32 Z
  } u;
  __shared__ float xbs[32][8];
  __shared__ float jacv[32];
  __shared__ float densl[32][8];
  const ushort* w1b = (const ushort*)(ws + WS_W1B);
  const ushort* w2b = (const ushort*)(ws + WS_W2B);
  const ushort* w3b = (const ushort*)(ws + WS_W3B);
  const int t = threadIdx.x, wv = t >> 6, l = t & 63, lr = l & 15, g = l >> 4;
  const int r0 = blockIdx.x * 32;

  if (t < 256) {
    int r = t >> 3, c2 = t & 7;
    xbs[r][c2] = fminf(x[(size_t)(r0 + r) * XSTR + PTS + c2], 1.f - 1e-6f);
  }
  if (t < 32) jacv[t] = x[(size_t)(r0 + t) * XSTR + 16];

  BF8 ax[2];
  #pragma unroll
  for (int mt = 0; mt < 2; mt++) {
    if (l < 16) {
      const float* xr = x + (size_t)(r0 + mt * 16 + lr) * XSTR;
      #pragma unroll
      for (int i2 = 0; i2 < 8; i2++) ax[mt].u[i2] = f2bf(xr[i2]);
    } else {
      #pragma unroll
      for (int i2 = 0; i2 < 8; i2++) ax[mt].u[i2] = 0;
    }
  }
  // ---- layer1 -> h1 ----
  #pragma unroll
  for (int j = 0; j < 2; j++) {
    int n = wv * 2 + j;
    BF8 bw; bw.v = *(const bfrag*)(w1b + ((size_t)n * 64 + l) * 8);
    int col = n * 16 + lr;
    float b1fv = ws[WS_B1F + col];
    f32x4 cini = {b1fv, b1fv, b1fv, b1fv};
    #pragma unroll
    for (int mt = 0; mt < 2; mt++) {
      f32x4 d = MFMA(ax[mt].v, bw.v, cini);
      #pragma unroll
      for (int r = 0; r < 4; r++) {
        int row = 4 * g + r;
        float h = fmaxf(d[r], 0.f);
        int byte = ((mt * 16 + row) * 256) * 2 + ((col * 2) ^ ((row & 7) << 4));
        *(ushort*)((char*)u.hb + byte) = f2bf(h);
      }
    }
  }
  __syncthreads();
  BF8 a2[2][8];
  #pragma unroll
  for (int mt = 0; mt < 2; mt++)
    #pragma unroll
    for (int s = 0; s < 8; s++) {
      int byte = ((mt * 16 + lr) * 256) * 2 + ((s * 64 + g * 16) ^ ((lr & 7) << 4));
      a2[mt][s].v = *(const bfrag*)((const char*)u.hb + byte);
    }
  __syncthreads();
  // ---- layer2 -> h2 ----
  #pragma unroll
  for (int j = 0; j < 2; j++) {
    int n = wv * 2 + j;
    f32x4 acc0 = {0.f, 0.f, 0.f, 0.f}, acc1 = {0.f, 0.f, 0.f, 0.f};
    #pragma unroll
    for (int s = 0; s < 8; s++) {
      BF8 bw; bw.v = *(const bfrag*)(w2b + (((size_t)n * 8 + s) * 64 + l) * 8);
      acc0 = MFMA(a2[0][s].v, bw.v, acc0);
      acc1 = MFMA(a2[1][s].v, bw.v, acc1);
    }
    int col = n * 16 + lr;
    float sc = ws[WS_SC2 + col], bi = ws[WS_BI2 + col];
    #pragma unroll
    for (int r = 0; r < 4; r++) {
      int row = 4 * g + r;
      float h0 = fmaxf(acc0[r] * sc + bi, 0.f);
      float h1v = fmaxf(acc1[r] * sc + bi, 0.f);
      int sw = (col * 2) ^ ((row & 7) << 4);
      *(ushort*)((char*)u.hb + ((0 * 16 + row) * 256) * 2 + sw) = f2bf(h0);
      *(ushort*)((char*)u.hb + ((1 * 16 + row) * 256) * 2 + sw) = f2bf(h1v);
    }
  }
  __syncthreads();
  BF8 a3[2][8];
  #pragma unroll
  for (int mt = 0; mt < 2; mt++)
    #pragma unroll
    for (int s = 0; s < 8; s++) {
      int byte = ((mt * 16 + lr) * 256) * 2 + ((s * 64 + g * 16) ^ ((lr & 7) << 4));
      a3[mt][s].v = *(const bfrag*)((const char*)u.hb + byte);
    }
  __syncthreads();   // all reads done; Z may now overwrite hb
  // ---- layer3: Z = h2 @ w3 + b3 (fp32 into LDS) ----
  for (int n = wv; n < 33; n += 8) {
    int col = n * 16 + lr;
    float bias = (col < OUTD) ? b3[col] : 0.f;
    f32x4 acc0 = {bias, bias, bias, bias}, acc1 = {bias, bias, bias, bias};
    #pragma unroll
    for (int s = 0; s < 8; s++) {
      BF8 bw; bw.v = *(const bfrag*)(w3b + (((size_t)n * 8 + s) * 64 + l) * 8);
      acc0 = MFMA(a3[0][s].v, bw.v, acc0);
      acc1 = MFMA(a3[1][s].v, bw.v, acc1);
    }
    if (col < OUTD) {
      #pragma unroll
      for (int r = 0; r < 4; r++) {
        u.Z[(4 * g + r) * 528 + col]      = acc0[r];
        u.Z[(16 + 4 * g + r) * 528 + col] = acc1[r];
      }
    }
  }
  __syncthreads();
  // ---- spline ----
  if (t < 256) {
    const int r = t >> 3, uu = t & 7;
    float* zp = &u.Z[r * 528 + uu * 65];
    const float xB = xbs[r][uu];
    float v0 = __expf(zp[0]); zp[0] = v0;
    float Wn = 0.f, Vtot = 0.f, vprev = v0;
    #pragma unroll
    for (int i = 0; i < NBINS; i++) {
      float v1 = __expf(zp[i + 1]); zp[i + 1] = v1;
      float w  = __expf(zp[NBINS + 1 + i]); zp[NBINS + 1 + i] = w;
      Wn += w; Vtot += 0.5f * (vprev + v1) * w; vprev = v1;
    }
    const float xT = xB * Wn;
    float cs = 0.f, csj = 0.f, U = 0.f; int j = 0;
    #pragma unroll
    for (int i = 0; i < NBINS; i++) {
      float w = zp[NBINS + 1 + i];
      float bar = 0.5f * (zp[i] + zp[i + 1]) * w;
      cs += w;
      if (cs <= xT) { j = i + 1; csj = cs; U += bar; }
    }
    const float Vj = zp[j], Vj1 = zp[j + 1], Wj = zp[NBINS + 1 + j];
    const float alpha = (xT - csj) / Wj;
    const float dV = Vj1 - Vj;
    const float yB = ((0.5f * alpha * alpha * dV + alpha * Vj) * Wj + U) / Vtot;
    const float dens = (Vj + alpha * dV) * Wn / Vtot;
    out[(size_t)(r0 + r) * XSTR + PTS + uu] = yB;
    densl[r][uu] = dens;
    out[(size_t)(r0 + r) * XSTR + uu] = x[(size_t)(r0 + r) * XSTR + uu];
  }
  __syncthreads();
  if (t < 32) {
    float p = jacv[t];
    #pragma unroll
    for (int uu = 0; uu < 8; uu++) p *= densl[t][uu];
    out[(size_t)(r0 + t) * XSTR + 16] = p;
  }
}

extern "C" void kernel_launch(void* const* d_in, const int* in_sizes, int n_in,
                              void* d_out, int out_size, void* d_ws, size_t ws_size,
                              hipStream_t stream) {
  (void)n_in; (void)out_size; (void)ws_size;
  const float* x  = (const float*)d_in[0];
  const float* g0 = (const float*)d_in[1];
  const float* b0 = (const float*)d_in[2];
  const float* w1 = (const float*)d_in[3];
  const float* g1 = (const float*)d_in[4];
  const float* b1 = (const float*)d_in[5];
  const float* w2 = (const float*)d_in[6];
  const float* g2 = (const float*)d_in[7];
  const float* b2 = (const float*)d_in[8];
  const float* w3 = (const float*)d_in[9];
  const float* b3 = (const float*)d_in[10];
  float* out = (float*)d_out;
  float* ws  = (float*)d_ws;
  const int B = in_sizes[0] / XSTR;
  const float invB = 1.0f / (float)B;

  hipMemsetAsync(d_ws, 0, WS_STATS_END * sizeof(float), stream);
  k_stats0<<<256, 256, 0, stream>>>(x, ws, B);
  k_pack_w2<<<(16 * 8 * 64 * 8) / 256, 256, 0, stream>>>(w2, ws);
  k_pack_w3<<<(33 * 8 * 64 * 8) / 256, 256, 0, stream>>>(w3, ws);
  k_fin0<<<1, 256, 0, stream>>>(w1, g0, b0, g1, b1, ws, invB);
  k_pack_w1<<<(16 * 64 * 8) / 256, 256, 0, stream>>>(w1, ws);
  k_stats2<<<512, 512, 0, stream>>>(x, ws, B);
  k_fin2<<<1, 256, 0, stream>>>(g2, b2, ws, invB);
  k_final<<<B / 32, 512, 0, stream>>>(x, b3, ws, out, B);
}

// Round 3
// 229.749 us; speedup vs baseline: 6.5920x; 3.2757x over previous
//
#include <hip/hip_runtime.h>
#include <math.h>

#define PTS   8
#define HID   256
#define OUTD  520
#define NBINS 32
#define XSTR  17
#define BN_EPS 1e-5f

typedef short bfrag __attribute__((ext_vector_type(8)));   // 8 bf16 (4 VGPRs)
typedef float f32x4 __attribute__((ext_vector_type(4)));

union BF8 { bfrag v; ushort u[8]; };

__device__ __forceinline__ ushort f2bf(float f) {          // RNE float->bf16
  uint u = __float_as_uint(f);
  return (ushort)((u + 0x7FFFu + ((u >> 16) & 1u)) >> 16);
}

#define MFMA(a, b, c) __builtin_amdgcn_mfma_f32_16x16x32_bf16((a), (b), (c), 0, 0, 0)

#define WREDUCE(a) { a += __shfl_xor(a,1); a += __shfl_xor(a,2); a += __shfl_xor(a,4); \
                     a += __shfl_xor(a,8); a += __shfl_xor(a,16); a += __shfl_xor(a,32); }

// ---- workspace float offsets ----
#define WS_SC0    0      // 8
#define WS_BI0    8      // 8
#define WS_SC1    16     // 256
#define WS_B1F    272    // 256
#define WS_SC2    528    // 256
#define WS_BI2    784    // 256
#define NC0       64
#define WS_P0     1040   // 64 copies x 44
#define NC2       32
#define WS_P2     3856   // 32 copies x 512 (sum[256], ss[256])
#define WS_STATS_END 20240
#define WS_W1B    20240  // 8192 ushorts
#define WS_W2B    24336  // 65536 ushorts
#define WS_W3B    57104  // 135168 ushorts

// ========== stats0: first + second (upper-tri) moments of xA ==========
__global__ __launch_bounds__(256) void k_stats0(const float* __restrict__ x,
                                                float* __restrict__ ws, int B) {
  float s[8], m[36];
  #pragma unroll
  for (int i = 0; i < 8; i++) s[i] = 0.f;
  #pragma unroll
  for (int k = 0; k < 36; k++) m[k] = 0.f;
  const int stride = gridDim.x * blockDim.x;
  for (int r = blockIdx.x * blockDim.x + threadIdx.x; r < B; r += stride) {
    const float* xr = x + (size_t)r * XSTR;
    float v[8];
    #pragma unroll
    for (int c = 0; c < 8; c++) v[c] = xr[c];
    int tri = 0;
    #pragma unroll
    for (int i = 0; i < 8; i++) {
      s[i] += v[i];
      #pragma unroll
      for (int j = i; j < 8; j++) { m[tri] += v[i] * v[j]; tri++; }
    }
  }
  #pragma unroll
  for (int i = 0; i < 8; i++) WREDUCE(s[i]);
  #pragma unroll
  for (int k = 0; k < 36; k++) WREDUCE(m[k]);
  const int wv = threadIdx.x >> 6;
  if ((threadIdx.x & 63) == 0) {
    float* base = ws + WS_P0 + (size_t)((blockIdx.x * 4 + wv) & (NC0 - 1)) * 44;
    #pragma unroll
    for (int i = 0; i < 8; i++) atomicAdd(&base[i], s[i]);
    #pragma unroll
    for (int k = 0; k < 36; k++) atomicAdd(&base[8 + k], m[k]);
  }
}

// ====== fin0: reduce copies; bn0 params + ANALYTIC bn1 stats + fused bias ======
__global__ void k_fin0(const float* __restrict__ w1, const float* __restrict__ g0,
                       const float* __restrict__ b0, const float* __restrict__ g1,
                       const float* __restrict__ b1, float* __restrict__ ws, float invB) {
  __shared__ float ssum[8], ssxx[8][8];
  __shared__ float smx[8], ssc[8], sbi[8], sma[8], scov[8][8];
  const int t = threadIdx.x;
  if (t < 44) {
    float v = 0.f;
    #pragma unroll 8
    for (int c = 0; c < NC0; c++) v += ws[WS_P0 + c * 44 + t];
    if (t < 8) ssum[t] = v;
    else {
      int k = t - 8, i = 0;
      while (k >= 8 - i) { k -= 8 - i; i++; }
      int j = i + k;
      ssxx[i][j] = v; ssxx[j][i] = v;
    }
  }
  __syncthreads();
  if (t < 8) {
    float mx  = ssum[t] * invB;
    float ex2 = ssxx[t][t] * invB;
    float var = ex2 - mx * mx;
    float sc  = g0[t] * rsqrtf(var + BN_EPS);
    float bi  = b0[t] - mx * sc;
    ws[WS_SC0 + t] = sc; ws[WS_BI0 + t] = bi;
    smx[t] = mx; ssc[t] = sc; sbi[t] = bi; sma[t] = sc * mx + bi;
  }
  __syncthreads();
  if (t < 64) {
    int i = t >> 3, j = t & 7;
    float e = ssc[i] * ssc[j] * (ssxx[i][j] * invB)
            + ssc[i] * smx[i] * sbi[j] + sbi[i] * ssc[j] * smx[j] + sbi[i] * sbi[j];
    scov[i][j] = e - sma[i] * sma[j];
  }
  __syncthreads();
  float wc[8];
  float m1 = 0.f, bvec = 0.f;
  #pragma unroll
  for (int k = 0; k < 8; k++) {
    wc[k] = w1[k * HID + t];
    m1   += sma[k] * wc[k];
    bvec += sbi[k] * wc[k];
  }
  float var1 = 0.f;
  #pragma unroll
  for (int i = 0; i < 8; i++)
    #pragma unroll
    for (int j = 0; j < 8; j++) var1 += wc[i] * wc[j] * scov[i][j];
  float sc1 = g1[t] * rsqrtf(var1 + BN_EPS);
  float bi1 = b1[t] - m1 * sc1;
  ws[WS_SC1 + t] = sc1;
  ws[WS_B1F + t] = bvec * sc1 + bi1;
}

// ================= weight fragment packing (bf16) =================
__global__ void k_pack_w1(const float* __restrict__ w1, float* __restrict__ ws) {
  int idx = blockIdx.x * blockDim.x + threadIdx.x;
  if (idx >= 16 * 64 * 8) return;
  int i = idx & 7, l = (idx >> 3) & 63, n = idx >> 9;
  int k = (l >> 4) * 8 + i, col = n * 16 + (l & 15);
  float v = (k < 8) ? ws[WS_SC0 + k] * w1[k * HID + col] * ws[WS_SC1 + col] : 0.f;
  ((ushort*)(ws + WS_W1B))[idx] = f2bf(v);
}

__global__ void k_pack_w2(const float* __restrict__ w2, float* __restrict__ ws) {
  int idx = blockIdx.x * blockDim.x + threadIdx.x;
  if (idx >= 16 * 8 * 64 * 8) return;
  int i = idx & 7, l = (idx >> 3) & 63, s = (idx >> 9) & 7, n = idx >> 12;
  int k = s * 32 + (l >> 4) * 8 + i, col = n * 16 + (l & 15);
  ((ushort*)(ws + WS_W2B))[idx] = f2bf(w2[k * HID + col]);
}

__global__ void k_pack_w3(const float* __restrict__ w3, float* __restrict__ ws) {
  int idx = blockIdx.x * blockDim.x + threadIdx.x;
  if (idx >= 33 * 8 * 64 * 8) return;
  int i = idx & 7, l = (idx >> 3) & 63, s = (idx >> 9) & 7, n = idx >> 12;
  int k = s * 32 + (l >> 4) * 8 + i, col = n * 16 + (l & 15);
  float v = (col < OUTD) ? w3[(size_t)k * OUTD + col] : 0.f;
  ((ushort*)(ws + WS_W3B))[idx] = f2bf(v);
}

// ================= stats2: bn2 moments via MFMA h2_pre =================
__global__ __launch_bounds__(512) void k_stats2(const float* __restrict__ x,
                                                float* __restrict__ ws, int B) {
  __shared__ ushort hb[2 * 16 * 256];
  const ushort* w1b = (const ushort*)(ws + WS_W1B);
  const ushort* w2b = (const ushort*)(ws + WS_W2B);
  const int t = threadIdx.x, wv = t >> 6, l = t & 63, lr = l & 15, g = l >> 4;
  float sacc[2] = {0.f, 0.f}, ssacc[2] = {0.f, 0.f};
  const int ntiles = B / 32;
  for (int tile = blockIdx.x; tile < ntiles; tile += gridDim.x) {
    const int r0 = tile * 32;
    BF8 ax[2];
    #pragma unroll
    for (int mt = 0; mt < 2; mt++) {
      if (l < 16) {
        const float* xr = x + (size_t)(r0 + mt * 16 + lr) * XSTR;
        #pragma unroll
        for (int i2 = 0; i2 < 8; i2++) ax[mt].u[i2] = f2bf(xr[i2]);
      } else {
        #pragma unroll
        for (int i2 = 0; i2 < 8; i2++) ax[mt].u[i2] = 0;
      }
    }
    // layer1 -> h1 (LDS, swizzled)
    #pragma unroll
    for (int j = 0; j < 2; j++) {
      int n = wv * 2 + j;
      BF8 bw; bw.v = *(const bfrag*)(w1b + ((size_t)n * 64 + l) * 8);
      int col = n * 16 + lr;
      float b1fv = ws[WS_B1F + col];
      f32x4 cini = {b1fv, b1fv, b1fv, b1fv};
      #pragma unroll
      for (int mt = 0; mt < 2; mt++) {
        f32x4 d = MFMA(ax[mt].v, bw.v, cini);
        #pragma unroll
        for (int r = 0; r < 4; r++) {
          int row = 4 * g + r;
          float h = fmaxf(d[r], 0.f);
          int byte = ((mt * 16 + row) * 256) * 2 + ((col * 2) ^ ((row & 7) << 4));
          *(ushort*)((char*)hb + byte) = f2bf(h);
        }
      }
    }
    __syncthreads();
    BF8 a2[2][8];
    #pragma unroll
    for (int mt = 0; mt < 2; mt++)
      #pragma unroll
      for (int s = 0; s < 8; s++) {
        int byte = ((mt * 16 + lr) * 256) * 2 + ((s * 64 + g * 16) ^ ((lr & 7) << 4));
        a2[mt][s].v = *(const bfrag*)((const char*)hb + byte);
      }
    __syncthreads();
    // layer2 h2_pre, accumulate moments
    #pragma unroll
    for (int j = 0; j < 2; j++) {
      int n = wv * 2 + j;
      f32x4 acc0 = {0.f, 0.f, 0.f, 0.f}, acc1 = {0.f, 0.f, 0.f, 0.f};
      #pragma unroll
      for (int s = 0; s < 8; s++) {
        BF8 bw; bw.v = *(const bfrag*)(w2b + (((size_t)n * 8 + s) * 64 + l) * 8);
        acc0 = MFMA(a2[0][s].v, bw.v, acc0);
        acc1 = MFMA(a2[1][s].v, bw.v, acc1);
      }
      float ls = 0.f, lss = 0.f;
      #pragma unroll
      for (int r = 0; r < 4; r++) {
        ls  += acc0[r] + acc1[r];
        lss += acc0[r] * acc0[r] + acc1[r] * acc1[r];
      }
      sacc[j] += ls; ssacc[j] += lss;
    }
  }
  #pragma unroll
  for (int j = 0; j < 2; j++) {
    float a = sacc[j], b = ssacc[j];
    a += __shfl_xor(a, 16); a += __shfl_xor(a, 32);
    b += __shfl_xor(b, 16); b += __shfl_xor(b, 32);
    if (g == 0) {
      int col = (wv * 2 + j) * 16 + lr;
      float* base = ws + WS_P2 + (size_t)(blockIdx.x & (NC2 - 1)) * 512;
      atomicAdd(&base[col], a);
      atomicAdd(&base[256 + col], b);
    }
  }
}

__global__ void k_fin2(const float* __restrict__ g2, const float* __restrict__ b2,
                       float* __restrict__ ws, float invB) {
  int t = threadIdx.x;
  float s = 0.f, ss = 0.f;
  #pragma unroll 8
  for (int c = 0; c < NC2; c++) {
    s  += ws[WS_P2 + c * 512 + t];
    ss += ws[WS_P2 + c * 512 + 256 + t];
  }
  float m   = s * invB;
  float var = ss * invB - m * m;
  float sc  = g2[t] * rsqrtf(var + BN_EPS);
  ws[WS_SC2 + t] = sc;
  ws[WS_BI2 + t] = b2[t] - m * sc;
}

// ================= final: full fused pipeline =================
__global__ __launch_bounds__(512) void k_final(const float* __restrict__ x,
                                               const float* __restrict__ b3,
                                               const float* __restrict__ ws,
                                               float* __restrict__ out, int B) {
  __shared__ union {
    ushort hb[2 * 16 * 256];   // 16 KB: h1 then h2 staging (swizzled)
    float  Z[32 * 528];        // 66 KB: fp32 Z
  } u;
  __shared__ float xbs[32][8];
  __shared__ float jacv[32];
  __shared__ float densl[32][8];
  const ushort* w1b = (const ushort*)(ws + WS_W1B);
  const ushort* w2b = (const ushort*)(ws + WS_W2B);
  const ushort* w3b = (const ushort*)(ws + WS_W3B);
  const int t = threadIdx.x, wv = t >> 6, l = t & 63, lr = l & 15, g = l >> 4;
  const int r0 = blockIdx.x * 32;

  if (t < 256) {
    int r = t >> 3, c2 = t & 7;
    xbs[r][c2] = fminf(x[(size_t)(r0 + r) * XSTR + PTS + c2], 1.f - 1e-6f);
  }
  if (t < 32) jacv[t] = x[(size_t)(r0 + t) * XSTR + 16];

  BF8 ax[2];
  #pragma unroll
  for (int mt = 0; mt < 2; mt++) {
    if (l < 16) {
      const float* xr = x + (size_t)(r0 + mt * 16 + lr) * XSTR;
      #pragma unroll
      for (int i2 = 0; i2 < 8; i2++) ax[mt].u[i2] = f2bf(xr[i2]);
    } else {
      #pragma unroll
      for (int i2 = 0; i2 < 8; i2++) ax[mt].u[i2] = 0;
    }
  }
  // ---- layer1 -> h1 ----
  #pragma unroll
  for (int j = 0; j < 2; j++) {
    int n = wv * 2 + j;
    BF8 bw; bw.v = *(const bfrag*)(w1b + ((size_t)n * 64 + l) * 8);
    int col = n * 16 + lr;
    float b1fv = ws[WS_B1F + col];
    f32x4 cini = {b1fv, b1fv, b1fv, b1fv};
    #pragma unroll
    for (int mt = 0; mt < 2; mt++) {
      f32x4 d = MFMA(ax[mt].v, bw.v, cini);
      #pragma unroll
      for (int r = 0; r < 4; r++) {
        int row = 4 * g + r;
        float h = fmaxf(d[r], 0.f);
        int byte = ((mt * 16 + row) * 256) * 2 + ((col * 2) ^ ((row & 7) << 4));
        *(ushort*)((char*)u.hb + byte) = f2bf(h);
      }
    }
  }
  __syncthreads();
  BF8 a2[2][8];
  #pragma unroll
  for (int mt = 0; mt < 2; mt++)
    #pragma unroll
    for (int s = 0; s < 8; s++) {
      int byte = ((mt * 16 + lr) * 256) * 2 + ((s * 64 + g * 16) ^ ((lr & 7) << 4));
      a2[mt][s].v = *(const bfrag*)((const char*)u.hb + byte);
    }
  __syncthreads();
  // ---- layer2 -> h2 ----
  #pragma unroll
  for (int j = 0; j < 2; j++) {
    int n = wv * 2 + j;
    f32x4 acc0 = {0.f, 0.f, 0.f, 0.f}, acc1 = {0.f, 0.f, 0.f, 0.f};
    #pragma unroll
    for (int s = 0; s < 8; s++) {
      BF8 bw; bw.v = *(const bfrag*)(w2b + (((size_t)n * 8 + s) * 64 + l) * 8);
      acc0 = MFMA(a2[0][s].v, bw.v, acc0);
      acc1 = MFMA(a2[1][s].v, bw.v, acc1);
    }
    int col = n * 16 + lr;
    float sc = ws[WS_SC2 + col], bi = ws[WS_BI2 + col];
    #pragma unroll
    for (int r = 0; r < 4; r++) {
      int row = 4 * g + r;
      float h0 = fmaxf(acc0[r] * sc + bi, 0.f);
      float h1v = fmaxf(acc1[r] * sc + bi, 0.f);
      int sw = (col * 2) ^ ((row & 7) << 4);
      *(ushort*)((char*)u.hb + ((0 * 16 + row) * 256) * 2 + sw) = f2bf(h0);
      *(ushort*)((char*)u.hb + ((1 * 16 + row) * 256) * 2 + sw) = f2bf(h1v);
    }
  }
  __syncthreads();
  BF8 a3[2][8];
  #pragma unroll
  for (int mt = 0; mt < 2; mt++)
    #pragma unroll
    for (int s = 0; s < 8; s++) {
      int byte = ((mt * 16 + lr) * 256) * 2 + ((s * 64 + g * 16) ^ ((lr & 7) << 4));
      a3[mt][s].v = *(const bfrag*)((const char*)u.hb + byte);
    }
  __syncthreads();   // all reads done; Z may now overwrite hb
  // ---- layer3: Z = h2 @ w3 + b3 (fp32 into LDS) ----
  for (int n = wv; n < 33; n += 8) {
    int col = n * 16 + lr;
    float bias = (col < OUTD) ? b3[col] : 0.f;
    f32x4 acc0 = {bias, bias, bias, bias}, acc1 = {bias, bias, bias, bias};
    #pragma unroll
    for (int s = 0; s < 8; s++) {
      BF8 bw; bw.v = *(const bfrag*)(w3b + (((size_t)n * 8 + s) * 64 + l) * 8);
      acc0 = MFMA(a3[0][s].v, bw.v, acc0);
      acc1 = MFMA(a3[1][s].v, bw.v, acc1);
    }
    if (col < OUTD) {
      #pragma unroll
      for (int r = 0; r < 4; r++) {
        u.Z[(4 * g + r) * 528 + col]      = acc0[r];
        u.Z[(16 + 4 * g + r) * 528 + col] = acc1[r];
      }
    }
  }
  __syncthreads();
  // ---- spline ----
  if (t < 256) {
    const int r = t >> 3, uu = t & 7;
    float* zp = &u.Z[r * 528 + uu * 65];
    const float xB = xbs[r][uu];
    float v0 = __expf(zp[0]); zp[0] = v0;
    float Wn = 0.f, Vtot = 0.f, vprev = v0;
    #pragma unroll
    for (int i = 0; i < NBINS; i++) {
      float v1 = __expf(zp[i + 1]); zp[i + 1] = v1;
      float w  = __expf(zp[NBINS + 1 + i]); zp[NBINS + 1 + i] = w;
      Wn += w; Vtot += 0.5f * (vprev + v1) * w; vprev = v1;
    }
    const float xT = xB * Wn;
    float cs = 0.f, csj = 0.f, U = 0.f; int j = 0;
    #pragma unroll
    for (int i = 0; i < NBINS; i++) {
      float w = zp[NBINS + 1 + i];
      float bar = 0.5f * (zp[i] + zp[i + 1]) * w;
      cs += w;
      if (cs <= xT) { j = i + 1; csj = cs; U += bar; }
    }
    const float Vj = zp[j], Vj1 = zp[j + 1], Wj = zp[NBINS + 1 + j];
    const float alpha = (xT - csj) / Wj;
    const float dV = Vj1 - Vj;
    const float yB = ((0.5f * alpha * alpha * dV + alpha * Vj) * Wj + U) / Vtot;
    const float dens = (Vj + alpha * dV) * Wn / Vtot;
    out[(size_t)(r0 + r) * XSTR + PTS + uu] = yB;
    densl[r][uu] = dens;
    out[(size_t)(r0 + r) * XSTR + uu] = x[(size_t)(r0 + r) * XSTR + uu];
  }
  __syncthreads();
  if (t < 32) {
    float p = jacv[t];
    #pragma unroll
    for (int uu = 0; uu < 8; uu++) p *= densl[t][uu];
    out[(size_t)(r0 + t) * XSTR + 16] = p;
  }
}

extern "C" void kernel_launch(void* const* d_in, const int* in_sizes, int n_in,
                              void* d_out, int out_size, void* d_ws, size_t ws_size,
                              hipStream_t stream) {
  (void)n_in; (void)out_size; (void)ws_size;
  const float* x  = (const float*)d_in[0];
  const float* g0 = (const float*)d_in[1];
  const float* b0 = (const float*)d_in[2];
  const float* w1 = (const float*)d_in[3];
  const float* g1 = (const float*)d_in[4];
  const float* b1 = (const float*)d_in[5];
  const float* w2 = (const float*)d_in[6];
  const float* g2 = (const float*)d_in[7];
  const float* b2 = (const float*)d_in[8];
  const float* w3 = (const float*)d_in[9];
  const float* b3 = (const float*)d_in[10];
  float* out = (float*)d_out;
  float* ws  = (float*)d_ws;
  const int B = in_sizes[0] / XSTR;
  const float invB = 1.0f / (float)B;

  hipMemsetAsync(d_ws, 0, WS_STATS_END * sizeof(float), stream);
  k_stats0<<<256, 256, 0, stream>>>(x, ws, B);
  k_pack_w2<<<(16 * 8 * 64 * 8) / 256, 256, 0, stream>>>(w2, ws);
  k_pack_w3<<<(33 * 8 * 64 * 8) / 256, 256, 0, stream>>>(w3, ws);
  k_fin0<<<1, 256, 0, stream>>>(w1, g0, b0, g1, b1, ws, invB);
  k_pack_w1<<<(16 * 64 * 8) / 256, 256, 0, stream>>>(w1, ws);
  k_stats2<<<512, 512, 0, stream>>>(x, ws, B);
  k_fin2<<<1, 256, 0, stream>>>(g2, b2, ws, invB);
  k_final<<<B / 32, 512, 0, stream>>>(x, b3, ws, out, B);
}

// Round 4
// 218.650 us; speedup vs baseline: 6.9266x; 1.0508x over previous
//
#include <hip/hip_runtime.h>
#include <math.h>

#define PTS   8
#define HID   256
#define OUTD  520
#define NBINS 32
#define XSTR  17
#define BN_EPS 1e-5f
#define ZSTR  548   // 548 % 32 == 4; with 65 % 32 == 1 both Z writes and spline reads are 2-per-bank (free)

typedef short bfrag __attribute__((ext_vector_type(8)));   // 8 bf16 (4 VGPRs)
typedef float f32x4 __attribute__((ext_vector_type(4)));

union BF8 { bfrag v; ushort u[8]; };

__device__ __forceinline__ ushort f2bf(float f) {          // RNE float->bf16
  uint u = __float_as_uint(f);
  return (ushort)((u + 0x7FFFu + ((u >> 16) & 1u)) >> 16);
}

#define MFMA(a, b, c) __builtin_amdgcn_mfma_f32_16x16x32_bf16((a), (b), (c), 0, 0, 0)

#define WREDUCE(a) { a += __shfl_xor(a,1); a += __shfl_xor(a,2); a += __shfl_xor(a,4); \
                     a += __shfl_xor(a,8); a += __shfl_xor(a,16); a += __shfl_xor(a,32); }

// ---- workspace float offsets ----
#define WS_SC0    0      // 8
#define WS_BI0    8      // 8
#define WS_SC1    16     // 256
#define WS_B1F    272    // 256
#define WS_SC2    528    // 256
#define WS_BI2    784    // 256
#define NC0       64
#define WS_P0     1040   // 64 copies x 44
#define NC2       32
#define WS_P2     3856   // 32 copies x 512 (sum[256], ss[256])
#define WS_STATS_END 20240
#define WS_W1B    20240  // 8192 ushorts
#define WS_W2B    24336  // 65536 ushorts
#define WS_W3B    57104  // 135168 ushorts

// ========== stats0: first + second (upper-tri) moments of xA ==========
__global__ __launch_bounds__(256) void k_stats0(const float* __restrict__ x,
                                                float* __restrict__ ws, int B) {
  float s[8], m[36];
  #pragma unroll
  for (int i = 0; i < 8; i++) s[i] = 0.f;
  #pragma unroll
  for (int k = 0; k < 36; k++) m[k] = 0.f;
  const int stride = gridDim.x * blockDim.x;
  for (int r = blockIdx.x * blockDim.x + threadIdx.x; r < B; r += stride) {
    const float* xr = x + (size_t)r * XSTR;
    float v[8];
    #pragma unroll
    for (int c = 0; c < 8; c++) v[c] = xr[c];
    int tri = 0;
    #pragma unroll
    for (int i = 0; i < 8; i++) {
      s[i] += v[i];
      #pragma unroll
      for (int j = i; j < 8; j++) { m[tri] += v[i] * v[j]; tri++; }
    }
  }
  #pragma unroll
  for (int i = 0; i < 8; i++) WREDUCE(s[i]);
  #pragma unroll
  for (int k = 0; k < 36; k++) WREDUCE(m[k]);
  const int wv = threadIdx.x >> 6;
  if ((threadIdx.x & 63) == 0) {
    float* base = ws + WS_P0 + (size_t)((blockIdx.x * 4 + wv) & (NC0 - 1)) * 44;
    #pragma unroll
    for (int i = 0; i < 8; i++) atomicAdd(&base[i], s[i]);
    #pragma unroll
    for (int k = 0; k < 36; k++) atomicAdd(&base[8 + k], m[k]);
  }
}

// ====== fin0: reduce copies; bn0 params + ANALYTIC bn1 stats + fused bias ======
__global__ void k_fin0(const float* __restrict__ w1, const float* __restrict__ g0,
                       const float* __restrict__ b0, const float* __restrict__ g1,
                       const float* __restrict__ b1, float* __restrict__ ws, float invB) {
  __shared__ float ssum[8], ssxx[8][8];
  __shared__ float smx[8], ssc[8], sbi[8], sma[8], scov[8][8];
  const int t = threadIdx.x;
  if (t < 44) {
    float v = 0.f;
    #pragma unroll 8
    for (int c = 0; c < NC0; c++) v += ws[WS_P0 + c * 44 + t];
    if (t < 8) ssum[t] = v;
    else {
      int k = t - 8, i = 0;
      while (k >= 8 - i) { k -= 8 - i; i++; }
      int j = i + k;
      ssxx[i][j] = v; ssxx[j][i] = v;
    }
  }
  __syncthreads();
  if (t < 8) {
    float mx  = ssum[t] * invB;
    float ex2 = ssxx[t][t] * invB;
    float var = ex2 - mx * mx;
    float sc  = g0[t] * rsqrtf(var + BN_EPS);
    float bi  = b0[t] - mx * sc;
    ws[WS_SC0 + t] = sc; ws[WS_BI0 + t] = bi;
    smx[t] = mx; ssc[t] = sc; sbi[t] = bi; sma[t] = sc * mx + bi;
  }
  __syncthreads();
  if (t < 64) {
    int i = t >> 3, j = t & 7;
    float e = ssc[i] * ssc[j] * (ssxx[i][j] * invB)
            + ssc[i] * smx[i] * sbi[j] + sbi[i] * ssc[j] * smx[j] + sbi[i] * sbi[j];
    scov[i][j] = e - sma[i] * sma[j];
  }
  __syncthreads();
  float wc[8];
  float m1 = 0.f, bvec = 0.f;
  #pragma unroll
  for (int k = 0; k < 8; k++) {
    wc[k] = w1[k * HID + t];
    m1   += sma[k] * wc[k];
    bvec += sbi[k] * wc[k];
  }
  float var1 = 0.f;
  #pragma unroll
  for (int i = 0; i < 8; i++)
    #pragma unroll
    for (int j = 0; j < 8; j++) var1 += wc[i] * wc[j] * scov[i][j];
  float sc1 = g1[t] * rsqrtf(var1 + BN_EPS);
  float bi1 = b1[t] - m1 * sc1;
  ws[WS_SC1 + t] = sc1;
  ws[WS_B1F + t] = bvec * sc1 + bi1;
}

// ================= weight fragment packing (bf16) =================
__global__ void k_pack_w1(const float* __restrict__ w1, float* __restrict__ ws) {
  int idx = blockIdx.x * blockDim.x + threadIdx.x;
  if (idx >= 16 * 64 * 8) return;
  int i = idx & 7, l = (idx >> 3) & 63, n = idx >> 9;
  int k = (l >> 4) * 8 + i, col = n * 16 + (l & 15);
  float v = (k < 8) ? ws[WS_SC0 + k] * w1[k * HID + col] * ws[WS_SC1 + col] : 0.f;
  ((ushort*)(ws + WS_W1B))[idx] = f2bf(v);
}

__global__ void k_pack_w2(const float* __restrict__ w2, float* __restrict__ ws) {
  int idx = blockIdx.x * blockDim.x + threadIdx.x;
  if (idx >= 16 * 8 * 64 * 8) return;
  int i = idx & 7, l = (idx >> 3) & 63, s = (idx >> 9) & 7, n = idx >> 12;
  int k = s * 32 + (l >> 4) * 8 + i, col = n * 16 + (l & 15);
  ((ushort*)(ws + WS_W2B))[idx] = f2bf(w2[k * HID + col]);
}

__global__ void k_pack_w3(const float* __restrict__ w3, float* __restrict__ ws) {
  int idx = blockIdx.x * blockDim.x + threadIdx.x;
  if (idx >= 33 * 8 * 64 * 8) return;
  int i = idx & 7, l = (idx >> 3) & 63, s = (idx >> 9) & 7, n = idx >> 12;
  int k = s * 32 + (l >> 4) * 8 + i, col = n * 16 + (l & 15);
  float v = (col < OUTD) ? w3[(size_t)k * OUTD + col] : 0.f;
  ((ushort*)(ws + WS_W3B))[idx] = f2bf(v);
}

// ================= stats2: bn2 moments via MFMA h2_pre =================
__global__ __launch_bounds__(512) void k_stats2(const float* __restrict__ x,
                                                float* __restrict__ ws, int B) {
  __shared__ ushort hb[2 * 16 * 256];
  const ushort* w1b = (const ushort*)(ws + WS_W1B);
  const ushort* w2b = (const ushort*)(ws + WS_W2B);
  const int t = threadIdx.x, wv = t >> 6, l = t & 63, lr = l & 15, g = l >> 4;
  float sacc[2] = {0.f, 0.f}, ssacc[2] = {0.f, 0.f};
  const int ntiles = B / 32;
  for (int tile = blockIdx.x; tile < ntiles; tile += gridDim.x) {
    const int r0 = tile * 32;
    BF8 ax[2];
    #pragma unroll
    for (int mt = 0; mt < 2; mt++) {
      if (l < 16) {
        const float* xr = x + (size_t)(r0 + mt * 16 + lr) * XSTR;
        #pragma unroll
        for (int i2 = 0; i2 < 8; i2++) ax[mt].u[i2] = f2bf(xr[i2]);
      } else {
        #pragma unroll
        for (int i2 = 0; i2 < 8; i2++) ax[mt].u[i2] = 0;
      }
    }
    // layer1 -> h1 (LDS, swizzled)
    #pragma unroll
    for (int j = 0; j < 2; j++) {
      int n = wv * 2 + j;
      BF8 bw; bw.v = *(const bfrag*)(w1b + ((size_t)n * 64 + l) * 8);
      int col = n * 16 + lr;
      float b1fv = ws[WS_B1F + col];
      f32x4 cini = {b1fv, b1fv, b1fv, b1fv};
      #pragma unroll
      for (int mt = 0; mt < 2; mt++) {
        f32x4 d = MFMA(ax[mt].v, bw.v, cini);
        #pragma unroll
        for (int r = 0; r < 4; r++) {
          int row = 4 * g + r;
          float h = fmaxf(d[r], 0.f);
          int byte = ((mt * 16 + row) * 256) * 2 + ((col * 2) ^ ((row & 7) << 4));
          *(ushort*)((char*)hb + byte) = f2bf(h);
        }
      }
    }
    __syncthreads();
    BF8 a2[2][8];
    #pragma unroll
    for (int mt = 0; mt < 2; mt++)
      #pragma unroll
      for (int s = 0; s < 8; s++) {
        int byte = ((mt * 16 + lr) * 256) * 2 + ((s * 64 + g * 16) ^ ((lr & 7) << 4));
        a2[mt][s].v = *(const bfrag*)((const char*)hb + byte);
      }
    __syncthreads();
    // layer2 h2_pre, accumulate moments
    #pragma unroll
    for (int j = 0; j < 2; j++) {
      int n = wv * 2 + j;
      f32x4 acc0 = {0.f, 0.f, 0.f, 0.f}, acc1 = {0.f, 0.f, 0.f, 0.f};
      #pragma unroll
      for (int s = 0; s < 8; s++) {
        BF8 bw; bw.v = *(const bfrag*)(w2b + (((size_t)n * 8 + s) * 64 + l) * 8);
        acc0 = MFMA(a2[0][s].v, bw.v, acc0);
        acc1 = MFMA(a2[1][s].v, bw.v, acc1);
      }
      float ls = 0.f, lss = 0.f;
      #pragma unroll
      for (int r = 0; r < 4; r++) {
        ls  += acc0[r] + acc1[r];
        lss += acc0[r] * acc0[r] + acc1[r] * acc1[r];
      }
      sacc[j] += ls; ssacc[j] += lss;
    }
  }
  #pragma unroll
  for (int j = 0; j < 2; j++) {
    float a = sacc[j], b = ssacc[j];
    a += __shfl_xor(a, 16); a += __shfl_xor(a, 32);
    b += __shfl_xor(b, 16); b += __shfl_xor(b, 32);
    if (g == 0) {
      int col = (wv * 2 + j) * 16 + lr;
      float* base = ws + WS_P2 + (size_t)(blockIdx.x & (NC2 - 1)) * 512;
      atomicAdd(&base[col], a);
      atomicAdd(&base[256 + col], b);
    }
  }
}

__global__ void k_fin2(const float* __restrict__ g2, const float* __restrict__ b2,
                       float* __restrict__ ws, float invB) {
  int t = threadIdx.x;
  float s = 0.f, ss = 0.f;
  #pragma unroll 8
  for (int c = 0; c < NC2; c++) {
    s  += ws[WS_P2 + c * 512 + t];
    ss += ws[WS_P2 + c * 512 + 256 + t];
  }
  float m   = s * invB;
  float var = ss * invB - m * m;
  float sc  = g2[t] * rsqrtf(var + BN_EPS);
  ws[WS_SC2 + t] = sc;
  ws[WS_BI2 + t] = b2[t] - m * sc;
}

// ================= final: full fused pipeline =================
__global__ __launch_bounds__(512) void k_final(const float* __restrict__ x,
                                               const float* __restrict__ b3,
                                               const float* __restrict__ ws,
                                               float* __restrict__ out, int B) {
  __shared__ union {
    ushort hb[2 * 16 * 256];   // 16 KB: h1 then h2 staging (swizzled)
    float  Z[32 * ZSTR];       // 70.1 KB: exp(Z), bank-conflict-free layout
  } u;
  __shared__ float xbs[32][8];
  __shared__ float jacv[32];
  __shared__ float densl[32][8];
  const ushort* w1b = (const ushort*)(ws + WS_W1B);
  const ushort* w2b = (const ushort*)(ws + WS_W2B);
  const ushort* w3b = (const ushort*)(ws + WS_W3B);
  const int t = threadIdx.x, wv = t >> 6, l = t & 63, lr = l & 15, g = l >> 4;
  const int r0 = blockIdx.x * 32;

  if (t < 256) {
    int r = t >> 3, c2 = t & 7;
    xbs[r][c2] = fminf(x[(size_t)(r0 + r) * XSTR + PTS + c2], 1.f - 1e-6f);
  }
  if (t < 32) jacv[t] = x[(size_t)(r0 + t) * XSTR + 16];

  BF8 ax[2];
  #pragma unroll
  for (int mt = 0; mt < 2; mt++) {
    if (l < 16) {
      const float* xr = x + (size_t)(r0 + mt * 16 + lr) * XSTR;
      #pragma unroll
      for (int i2 = 0; i2 < 8; i2++) ax[mt].u[i2] = f2bf(xr[i2]);
    } else {
      #pragma unroll
      for (int i2 = 0; i2 < 8; i2++) ax[mt].u[i2] = 0;
    }
  }
  // ---- layer1 -> h1 ----
  #pragma unroll
  for (int j = 0; j < 2; j++) {
    int n = wv * 2 + j;
    BF8 bw; bw.v = *(const bfrag*)(w1b + ((size_t)n * 64 + l) * 8);
    int col = n * 16 + lr;
    float b1fv = ws[WS_B1F + col];
    f32x4 cini = {b1fv, b1fv, b1fv, b1fv};
    #pragma unroll
    for (int mt = 0; mt < 2; mt++) {
      f32x4 d = MFMA(ax[mt].v, bw.v, cini);
      #pragma unroll
      for (int r = 0; r < 4; r++) {
        int row = 4 * g + r;
        float h = fmaxf(d[r], 0.f);
        int byte = ((mt * 16 + row) * 256) * 2 + ((col * 2) ^ ((row & 7) << 4));
        *(ushort*)((char*)u.hb + byte) = f2bf(h);
      }
    }
  }
  __syncthreads();
  BF8 a2[2][8];
  #pragma unroll
  for (int mt = 0; mt < 2; mt++)
    #pragma unroll
    for (int s = 0; s < 8; s++) {
      int byte = ((mt * 16 + lr) * 256) * 2 + ((s * 64 + g * 16) ^ ((lr & 7) << 4));
      a2[mt][s].v = *(const bfrag*)((const char*)u.hb + byte);
    }
  __syncthreads();
  // ---- layer2 -> h2 ----
  #pragma unroll
  for (int j = 0; j < 2; j++) {
    int n = wv * 2 + j;
    f32x4 acc0 = {0.f, 0.f, 0.f, 0.f}, acc1 = {0.f, 0.f, 0.f, 0.f};
    #pragma unroll
    for (int s = 0; s < 8; s++) {
      BF8 bw; bw.v = *(const bfrag*)(w2b + (((size_t)n * 8 + s) * 64 + l) * 8);
      acc0 = MFMA(a2[0][s].v, bw.v, acc0);
      acc1 = MFMA(a2[1][s].v, bw.v, acc1);
    }
    int col = n * 16 + lr;
    float sc = ws[WS_SC2 + col], bi = ws[WS_BI2 + col];
    #pragma unroll
    for (int r = 0; r < 4; r++) {
      int row = 4 * g + r;
      float h0 = fmaxf(acc0[r] * sc + bi, 0.f);
      float h1v = fmaxf(acc1[r] * sc + bi, 0.f);
      int sw = (col * 2) ^ ((row & 7) << 4);
      *(ushort*)((char*)u.hb + ((0 * 16 + row) * 256) * 2 + sw) = f2bf(h0);
      *(ushort*)((char*)u.hb + ((1 * 16 + row) * 256) * 2 + sw) = f2bf(h1v);
    }
  }
  __syncthreads();
  BF8 a3[2][8];
  #pragma unroll
  for (int mt = 0; mt < 2; mt++)
    #pragma unroll
    for (int s = 0; s < 8; s++) {
      int byte = ((mt * 16 + lr) * 256) * 2 + ((s * 64 + g * 16) ^ ((lr & 7) << 4));
      a3[mt][s].v = *(const bfrag*)((const char*)u.hb + byte);
    }
  __syncthreads();   // all reads done; Z may now overwrite hb
  // ---- layer3: expZ = exp(h2 @ w3 + b3) (fp32 into LDS, conflict-free layout) ----
  // Z write bank = (4*row + col) % 32 -> exact 2-per-bank cover per store (free).
  // exp fused here: runs on all 8 waves instead of 4 in the spline phase.
  for (int n = wv; n < 33; n += 8) {
    int col = n * 16 + lr;
    float bias = (col < OUTD) ? b3[col] : 0.f;
    f32x4 acc0 = {bias, bias, bias, bias}, acc1 = {bias, bias, bias, bias};
    #pragma unroll
    for (int s = 0; s < 8; s++) {
      BF8 bw; bw.v = *(const bfrag*)(w3b + (((size_t)n * 8 + s) * 64 + l) * 8);
      acc0 = MFMA(a3[0][s].v, bw.v, acc0);
      acc1 = MFMA(a3[1][s].v, bw.v, acc1);
    }
    if (col < OUTD) {
      #pragma unroll
      for (int r = 0; r < 4; r++) {
        u.Z[(4 * g + r) * ZSTR + col]      = __expf(acc0[r]);
        u.Z[(16 + 4 * g + r) * ZSTR + col] = __expf(acc1[r]);
      }
    }
  }
  __syncthreads();
  // ---- spline (values already exponentiated; reads are 2-per-bank = free) ----
  if (t < 256) {
    const int r = t >> 3, uu = t & 7;
    const float* zp = &u.Z[r * ZSTR + uu * 65];
    const float xB = xbs[r][uu];
    float vprev = zp[0];
    float Wn = 0.f, Vtot = 0.f;
    #pragma unroll
    for (int i = 0; i < NBINS; i++) {
      float v1 = zp[i + 1];
      float w  = zp[NBINS + 1 + i];
      Wn += w; Vtot += 0.5f * (vprev + v1) * w; vprev = v1;
    }
    const float xT = xB * Wn;
    float cs = 0.f, csj = 0.f, U = 0.f; int j = 0;
    #pragma unroll
    for (int i = 0; i < NBINS; i++) {
      float w = zp[NBINS + 1 + i];
      float bar = 0.5f * (zp[i] + zp[i + 1]) * w;
      cs += w;
      if (cs <= xT) { j = i + 1; csj = cs; U += bar; }
    }
    const float Vj = zp[j], Vj1 = zp[j + 1], Wj = zp[NBINS + 1 + j];
    const float alpha = (xT - csj) / Wj;
    const float dV = Vj1 - Vj;
    const float yB = ((0.5f * alpha * alpha * dV + alpha * Vj) * Wj + U) / Vtot;
    const float dens = (Vj + alpha * dV) * Wn / Vtot;
    out[(size_t)(r0 + r) * XSTR + PTS + uu] = yB;
    densl[r][uu] = dens;
    out[(size_t)(r0 + r) * XSTR + uu] = x[(size_t)(r0 + r) * XSTR + uu];
  }
  __syncthreads();
  if (t < 32) {
    float p = jacv[t];
    #pragma unroll
    for (int uu = 0; uu < 8; uu++) p *= densl[t][uu];
    out[(size_t)(r0 + t) * XSTR + 16] = p;
  }
}

extern "C" void kernel_launch(void* const* d_in, const int* in_sizes, int n_in,
                              void* d_out, int out_size, void* d_ws, size_t ws_size,
                              hipStream_t stream) {
  (void)n_in; (void)out_size; (void)ws_size;
  const float* x  = (const float*)d_in[0];
  const float* g0 = (const float*)d_in[1];
  const float* b0 = (const float*)d_in[2];
  const float* w1 = (const float*)d_in[3];
  const float* g1 = (const float*)d_in[4];
  const float* b1 = (const float*)d_in[5];
  const float* w2 = (const float*)d_in[6];
  const float* g2 = (const float*)d_in[7];
  const float* b2 = (const float*)d_in[8];
  const float* w3 = (const float*)d_in[9];
  const float* b3 = (const float*)d_in[10];
  float* out = (float*)d_out;
  float* ws  = (float*)d_ws;
  const int B = in_sizes[0] / XSTR;
  const float invB = 1.0f / (float)B;

  hipMemsetAsync(d_ws, 0, WS_STATS_END * sizeof(float), stream);
  k_stats0<<<256, 256, 0, stream>>>(x, ws, B);
  k_pack_w2<<<(16 * 8 * 64 * 8) / 256, 256, 0, stream>>>(w2, ws);
  k_pack_w3<<<(33 * 8 * 64 * 8) / 256, 256, 0, stream>>>(w3, ws);
  k_fin0<<<1, 256, 0, stream>>>(w1, g0, b0, g1, b1, ws, invB);
  k_pack_w1<<<(16 * 64 * 8) / 256, 256, 0, stream>>>(w1, ws);
  k_stats2<<<512, 512, 0, stream>>>(x, ws, B);
  k_fin2<<<1, 256, 0, stream>>>(g2, b2, ws, invB);
  k_final<<<B / 32, 512, 0, stream>>>(x, b3, ws, out, B);
}

// Round 5
// 205.326 us; speedup vs baseline: 7.3761x; 1.0649x over previous
//
#include <hip/hip_runtime.h>
#include <math.h>

#define PTS   8
#define HID   256
#define OUTD  520
#define NBINS 32
#define XSTR  17
#define BN_EPS 1e-5f
#define ZH    536   // fp16 Z stride (row-major [32][ZH]); 536/2=268≡12 mod 32 spreads banks
#define LOG2E 1.44269504088896f

typedef short bfrag __attribute__((ext_vector_type(8)));   // 8 bf16 (4 VGPRs)
typedef float f32x4 __attribute__((ext_vector_type(4)));

union BF8 { bfrag v; ushort u[8]; };

__device__ __forceinline__ ushort f2bf(float f) {          // RNE float->bf16
  uint u = __float_as_uint(f);
  return (ushort)((u + 0x7FFFu + ((u >> 16) & 1u)) >> 16);
}

#if defined(__has_builtin)
#if __has_builtin(__builtin_amdgcn_exp2f)
__device__ __forceinline__ float fexp2(float x) { return __builtin_amdgcn_exp2f(x); }
#else
__device__ __forceinline__ float fexp2(float x) { return exp2f(x); }
#endif
#else
__device__ __forceinline__ float fexp2(float x) { return exp2f(x); }
#endif

#define MFMA(a, b, c) __builtin_amdgcn_mfma_f32_16x16x32_bf16((a), (b), (c), 0, 0, 0)

#define WREDUCE(a) { a += __shfl_xor(a,1); a += __shfl_xor(a,2); a += __shfl_xor(a,4); \
                     a += __shfl_xor(a,8); a += __shfl_xor(a,16); a += __shfl_xor(a,32); }

// ---- workspace float offsets ----
#define WS_SC0    0      // 8
#define WS_BI0    8      // 8
#define WS_SC1    16     // 256
#define WS_B1F    272    // 256
#define WS_SC2    528    // 256
#define WS_BI2    784    // 256
#define NC0       64
#define WS_P0     1040   // 64 copies x 44
#define NC2       32
#define WS_P2     3856   // 32 copies x 512 (sum[256], ss[256])
#define WS_STATS_END 20240
#define WS_W1B    20240  // 8192 ushorts
#define WS_W2B    24336  // 65536 ushorts
#define WS_W3B    57104  // 135168 ushorts

// ========== stats0: first + second (upper-tri) moments of xA ==========
__global__ __launch_bounds__(256) void k_stats0(const float* __restrict__ x,
                                                float* __restrict__ ws, int B) {
  float s[8], m[36];
  #pragma unroll
  for (int i = 0; i < 8; i++) s[i] = 0.f;
  #pragma unroll
  for (int k = 0; k < 36; k++) m[k] = 0.f;
  const int stride = gridDim.x * blockDim.x;
  for (int r = blockIdx.x * blockDim.x + threadIdx.x; r < B; r += stride) {
    const float* xr = x + (size_t)r * XSTR;
    float v[8];
    #pragma unroll
    for (int c = 0; c < 8; c++) v[c] = xr[c];
    int tri = 0;
    #pragma unroll
    for (int i = 0; i < 8; i++) {
      s[i] += v[i];
      #pragma unroll
      for (int j = i; j < 8; j++) { m[tri] += v[i] * v[j]; tri++; }
    }
  }
  #pragma unroll
  for (int i = 0; i < 8; i++) WREDUCE(s[i]);
  #pragma unroll
  for (int k = 0; k < 36; k++) WREDUCE(m[k]);
  const int wv = threadIdx.x >> 6;
  if ((threadIdx.x & 63) == 0) {
    float* base = ws + WS_P0 + (size_t)((blockIdx.x * 4 + wv) & (NC0 - 1)) * 44;
    #pragma unroll
    for (int i = 0; i < 8; i++) atomicAdd(&base[i], s[i]);
    #pragma unroll
    for (int k = 0; k < 36; k++) atomicAdd(&base[8 + k], m[k]);
  }
}

// ====== fin0: reduce copies; bn0 params + ANALYTIC bn1 stats + fused bias ======
__global__ void k_fin0(const float* __restrict__ w1, const float* __restrict__ g0,
                       const float* __restrict__ b0, const float* __restrict__ g1,
                       const float* __restrict__ b1, float* __restrict__ ws, float invB) {
  __shared__ float ssum[8], ssxx[8][8];
  __shared__ float smx[8], ssc[8], sbi[8], sma[8], scov[8][8];
  const int t = threadIdx.x;
  if (t < 44) {
    float v = 0.f;
    #pragma unroll 8
    for (int c = 0; c < NC0; c++) v += ws[WS_P0 + c * 44 + t];
    if (t < 8) ssum[t] = v;
    else {
      int k = t - 8, i = 0;
      while (k >= 8 - i) { k -= 8 - i; i++; }
      int j = i + k;
      ssxx[i][j] = v; ssxx[j][i] = v;
    }
  }
  __syncthreads();
  if (t < 8) {
    float mx  = ssum[t] * invB;
    float ex2 = ssxx[t][t] * invB;
    float var = ex2 - mx * mx;
    float sc  = g0[t] * rsqrtf(var + BN_EPS);
    float bi  = b0[t] - mx * sc;
    ws[WS_SC0 + t] = sc; ws[WS_BI0 + t] = bi;
    smx[t] = mx; ssc[t] = sc; sbi[t] = bi; sma[t] = sc * mx + bi;
  }
  __syncthreads();
  if (t < 64) {
    int i = t >> 3, j = t & 7;
    float e = ssc[i] * ssc[j] * (ssxx[i][j] * invB)
            + ssc[i] * smx[i] * sbi[j] + sbi[i] * ssc[j] * smx[j] + sbi[i] * sbi[j];
    scov[i][j] = e - sma[i] * sma[j];
  }
  __syncthreads();
  float wc[8];
  float m1 = 0.f, bvec = 0.f;
  #pragma unroll
  for (int k = 0; k < 8; k++) {
    wc[k] = w1[k * HID + t];
    m1   += sma[k] * wc[k];
    bvec += sbi[k] * wc[k];
  }
  float var1 = 0.f;
  #pragma unroll
  for (int i = 0; i < 8; i++)
    #pragma unroll
    for (int j = 0; j < 8; j++) var1 += wc[i] * wc[j] * scov[i][j];
  float sc1 = g1[t] * rsqrtf(var1 + BN_EPS);
  float bi1 = b1[t] - m1 * sc1;
  ws[WS_SC1 + t] = sc1;
  ws[WS_B1F + t] = bvec * sc1 + bi1;
}

// ================= weight fragment packing (bf16) =================
__global__ void k_pack_w1(const float* __restrict__ w1, float* __restrict__ ws) {
  int idx = blockIdx.x * blockDim.x + threadIdx.x;
  if (idx >= 16 * 64 * 8) return;
  int i = idx & 7, l = (idx >> 3) & 63, n = idx >> 9;
  int k = (l >> 4) * 8 + i, col = n * 16 + (l & 15);
  float v = (k < 8) ? ws[WS_SC0 + k] * w1[k * HID + col] * ws[WS_SC1 + col] : 0.f;
  ((ushort*)(ws + WS_W1B))[idx] = f2bf(v);
}

__global__ void k_pack_w2(const float* __restrict__ w2, float* __restrict__ ws) {
  int idx = blockIdx.x * blockDim.x + threadIdx.x;
  if (idx >= 16 * 8 * 64 * 8) return;
  int i = idx & 7, l = (idx >> 3) & 63, s = (idx >> 9) & 7, n = idx >> 12;
  int k = s * 32 + (l >> 4) * 8 + i, col = n * 16 + (l & 15);
  ((ushort*)(ws + WS_W2B))[idx] = f2bf(w2[k * HID + col]);
}

// w3 is packed pre-scaled by log2(e) so layer3 computes Z*log2e and exp is a bare v_exp_f32
__global__ void k_pack_w3(const float* __restrict__ w3, float* __restrict__ ws) {
  int idx = blockIdx.x * blockDim.x + threadIdx.x;
  if (idx >= 33 * 8 * 64 * 8) return;
  int i = idx & 7, l = (idx >> 3) & 63, s = (idx >> 9) & 7, n = idx >> 12;
  int k = s * 32 + (l >> 4) * 8 + i, col = n * 16 + (l & 15);
  float v = (col < OUTD) ? w3[(size_t)k * OUTD + col] * LOG2E : 0.f;
  ((ushort*)(ws + WS_W3B))[idx] = f2bf(v);
}

// ================= stats2: bn2 moments via MFMA h2_pre =================
__global__ __launch_bounds__(512) void k_stats2(const float* __restrict__ x,
                                                float* __restrict__ ws, int B) {
  __shared__ ushort hb[2 * 16 * 256];
  const ushort* w1b = (const ushort*)(ws + WS_W1B);
  const ushort* w2b = (const ushort*)(ws + WS_W2B);
  const int t = threadIdx.x, wv = t >> 6, l = t & 63, lr = l & 15, g = l >> 4;
  float sacc[2] = {0.f, 0.f}, ssacc[2] = {0.f, 0.f};
  const int ntiles = B / 32;
  for (int tile = blockIdx.x; tile < ntiles; tile += gridDim.x) {
    const int r0 = tile * 32;
    BF8 ax[2];
    #pragma unroll
    for (int mt = 0; mt < 2; mt++) {
      if (l < 16) {
        const float* xr = x + (size_t)(r0 + mt * 16 + lr) * XSTR;
        #pragma unroll
        for (int i2 = 0; i2 < 8; i2++) ax[mt].u[i2] = f2bf(xr[i2]);
      } else {
        #pragma unroll
        for (int i2 = 0; i2 < 8; i2++) ax[mt].u[i2] = 0;
      }
    }
    // layer1 -> h1 (LDS, swizzled)
    #pragma unroll
    for (int j = 0; j < 2; j++) {
      int n = wv * 2 + j;
      BF8 bw; bw.v = *(const bfrag*)(w1b + ((size_t)n * 64 + l) * 8);
      int col = n * 16 + lr;
      float b1fv = ws[WS_B1F + col];
      f32x4 cini = {b1fv, b1fv, b1fv, b1fv};
      #pragma unroll
      for (int mt = 0; mt < 2; mt++) {
        f32x4 d = MFMA(ax[mt].v, bw.v, cini);
        #pragma unroll
        for (int r = 0; r < 4; r++) {
          int row = 4 * g + r;
          float h = fmaxf(d[r], 0.f);
          int byte = ((mt * 16 + row) * 256) * 2 + ((col * 2) ^ ((row & 7) << 4));
          *(ushort*)((char*)hb + byte) = f2bf(h);
        }
      }
    }
    __syncthreads();
    BF8 a2[2][8];
    #pragma unroll
    for (int mt = 0; mt < 2; mt++)
      #pragma unroll
      for (int s = 0; s < 8; s++) {
        int byte = ((mt * 16 + lr) * 256) * 2 + ((s * 64 + g * 16) ^ ((lr & 7) << 4));
        a2[mt][s].v = *(const bfrag*)((const char*)hb + byte);
      }
    __syncthreads();
    // layer2 h2_pre, accumulate moments
    #pragma unroll
    for (int j = 0; j < 2; j++) {
      int n = wv * 2 + j;
      f32x4 acc0 = {0.f, 0.f, 0.f, 0.f}, acc1 = {0.f, 0.f, 0.f, 0.f};
      #pragma unroll
      for (int s = 0; s < 8; s++) {
        BF8 bw; bw.v = *(const bfrag*)(w2b + (((size_t)n * 8 + s) * 64 + l) * 8);
        acc0 = MFMA(a2[0][s].v, bw.v, acc0);
        acc1 = MFMA(a2[1][s].v, bw.v, acc1);
      }
      float ls = 0.f, lss = 0.f;
      #pragma unroll
      for (int r = 0; r < 4; r++) {
        ls  += acc0[r] + acc1[r];
        lss += acc0[r] * acc0[r] + acc1[r] * acc1[r];
      }
      sacc[j] += ls; ssacc[j] += lss;
    }
  }
  #pragma unroll
  for (int j = 0; j < 2; j++) {
    float a = sacc[j], b = ssacc[j];
    a += __shfl_xor(a, 16); a += __shfl_xor(a, 32);
    b += __shfl_xor(b, 16); b += __shfl_xor(b, 32);
    if (g == 0) {
      int col = (wv * 2 + j) * 16 + lr;
      float* base = ws + WS_P2 + (size_t)(blockIdx.x & (NC2 - 1)) * 512;
      atomicAdd(&base[col], a);
      atomicAdd(&base[256 + col], b);
    }
  }
}

__global__ void k_fin2(const float* __restrict__ g2, const float* __restrict__ b2,
                       float* __restrict__ ws, float invB) {
  int t = threadIdx.x;
  float s = 0.f, ss = 0.f;
  #pragma unroll 8
  for (int c = 0; c < NC2; c++) {
    s  += ws[WS_P2 + c * 512 + t];
    ss += ws[WS_P2 + c * 512 + 256 + t];
  }
  float m   = s * invB;
  float var = ss * invB - m * m;
  float sc  = g2[t] * rsqrtf(var + BN_EPS);
  ws[WS_SC2 + t] = sc;
  ws[WS_BI2 + t] = b2[t] - m * sc;
}

// ================= final: full fused pipeline =================
__global__ __launch_bounds__(512) void k_final(const float* __restrict__ x,
                                               const float* __restrict__ b3,
                                               const float* __restrict__ ws,
                                               float* __restrict__ out, int B) {
  __shared__ union {
    ushort   hb[2 * 16 * 256];   // 16 KB: h1 then h2 staging (swizzled)
    _Float16 Zh[32 * ZH];        // 33.5 KB: exp2(Z*log2e) in fp16
  } u;
  __shared__ float xbs[32][8];
  __shared__ float jacv[32];
  __shared__ float densl[32][8];
  const ushort* w1b = (const ushort*)(ws + WS_W1B);
  const ushort* w2b = (const ushort*)(ws + WS_W2B);
  const ushort* w3b = (const ushort*)(ws + WS_W3B);
  const int t = threadIdx.x, wv = t >> 6, l = t & 63, lr = l & 15, g = l >> 4;
  const int r0 = blockIdx.x * 32;

  if (t < 256) {
    int r = t >> 3, c2 = t & 7;
    xbs[r][c2] = fminf(x[(size_t)(r0 + r) * XSTR + PTS + c2], 1.f - 1e-6f);
  }
  if (t < 32) jacv[t] = x[(size_t)(r0 + t) * XSTR + 16];

  BF8 ax[2];
  #pragma unroll
  for (int mt = 0; mt < 2; mt++) {
    if (l < 16) {
      const float* xr = x + (size_t)(r0 + mt * 16 + lr) * XSTR;
      #pragma unroll
      for (int i2 = 0; i2 < 8; i2++) ax[mt].u[i2] = f2bf(xr[i2]);
    } else {
      #pragma unroll
      for (int i2 = 0; i2 < 8; i2++) ax[mt].u[i2] = 0;
    }
  }
  // ---- layer1 -> h1 ----
  #pragma unroll
  for (int j = 0; j < 2; j++) {
    int n = wv * 2 + j;
    BF8 bw; bw.v = *(const bfrag*)(w1b + ((size_t)n * 64 + l) * 8);
    int col = n * 16 + lr;
    float b1fv = ws[WS_B1F + col];
    f32x4 cini = {b1fv, b1fv, b1fv, b1fv};
    #pragma unroll
    for (int mt = 0; mt < 2; mt++) {
      f32x4 d = MFMA(ax[mt].v, bw.v, cini);
      #pragma unroll
      for (int r = 0; r < 4; r++) {
        int row = 4 * g + r;
        float h = fmaxf(d[r], 0.f);
        int byte = ((mt * 16 + row) * 256) * 2 + ((col * 2) ^ ((row & 7) << 4));
        *(ushort*)((char*)u.hb + byte) = f2bf(h);
      }
    }
  }
  __syncthreads();
  BF8 a2[2][8];
  #pragma unroll
  for (int mt = 0; mt < 2; mt++)
    #pragma unroll
    for (int s = 0; s < 8; s++) {
      int byte = ((mt * 16 + lr) * 256) * 2 + ((s * 64 + g * 16) ^ ((lr & 7) << 4));
      a2[mt][s].v = *(const bfrag*)((const char*)u.hb + byte);
    }
  __syncthreads();
  // ---- layer2 -> h2 ----
  #pragma unroll
  for (int j = 0; j < 2; j++) {
    int n = wv * 2 + j;
    f32x4 acc0 = {0.f, 0.f, 0.f, 0.f}, acc1 = {0.f, 0.f, 0.f, 0.f};
    #pragma unroll
    for (int s = 0; s < 8; s++) {
      BF8 bw; bw.v = *(const bfrag*)(w2b + (((size_t)n * 8 + s) * 64 + l) * 8);
      acc0 = MFMA(a2[0][s].v, bw.v, acc0);
      acc1 = MFMA(a2[1][s].v, bw.v, acc1);
    }
    int col = n * 16 + lr;
    float sc = ws[WS_SC2 + col], bi = ws[WS_BI2 + col];
    #pragma unroll
    for (int r = 0; r < 4; r++) {
      int row = 4 * g + r;
      float h0 = fmaxf(acc0[r] * sc + bi, 0.f);
      float h1v = fmaxf(acc1[r] * sc + bi, 0.f);
      int sw = (col * 2) ^ ((row & 7) << 4);
      *(ushort*)((char*)u.hb + ((0 * 16 + row) * 256) * 2 + sw) = f2bf(h0);
      *(ushort*)((char*)u.hb + ((1 * 16 + row) * 256) * 2 + sw) = f2bf(h1v);
    }
  }
  __syncthreads();
  BF8 a3[2][8];
  #pragma unroll
  for (int mt = 0; mt < 2; mt++)
    #pragma unroll
    for (int s = 0; s < 8; s++) {
      int byte = ((mt * 16 + lr) * 256) * 2 + ((s * 64 + g * 16) ^ ((lr & 7) << 4));
      a3[mt][s].v = *(const bfrag*)((const char*)u.hb + byte);
    }
  __syncthreads();   // all reads done; Zh may now overwrite hb
  // ---- layer3: Zh = exp2(h2 @ (w3*log2e) + b3*log2e) as fp16 into LDS ----
  for (int n = wv; n < 33; n += 8) {
    int col = n * 16 + lr;
    float bias = (col < OUTD) ? b3[col] * LOG2E : 0.f;
    f32x4 acc0 = {bias, bias, bias, bias}, acc1 = {bias, bias, bias, bias};
    #pragma unroll
    for (int s = 0; s < 8; s++) {
      BF8 bw; bw.v = *(const bfrag*)(w3b + (((size_t)n * 8 + s) * 64 + l) * 8);
      acc0 = MFMA(a3[0][s].v, bw.v, acc0);
      acc1 = MFMA(a3[1][s].v, bw.v, acc1);
    }
    if (col < OUTD) {
      #pragma unroll
      for (int r = 0; r < 4; r++) {
        u.Zh[(4 * g + r) * ZH + col]      = (_Float16)fexp2(acc0[r]);
        u.Zh[(16 + 4 * g + r) * ZH + col] = (_Float16)fexp2(acc1[r]);
      }
    }
  }
  __syncthreads();
  // ---- spline (values already exponentiated, fp16 in LDS) ----
  if (t < 256) {
    const int r = t >> 3, uu = t & 7;
    const _Float16* zp = &u.Zh[r * ZH + uu * 65];
    const float xB = xbs[r][uu];
    float vprev = (float)zp[0];
    float Wn = 0.f, Vtot = 0.f;
    #pragma unroll
    for (int i = 0; i < NBINS; i++) {
      float v1 = (float)zp[i + 1];
      float w  = (float)zp[NBINS + 1 + i];
      Wn += w; Vtot += 0.5f * (vprev + v1) * w; vprev = v1;
    }
    const float xT = xB * Wn;
    float cs = 0.f, csj = 0.f, U = 0.f; int j = 0;
    #pragma unroll
    for (int i = 0; i < NBINS; i++) {
      float w = (float)zp[NBINS + 1 + i];
      float bar = 0.5f * ((float)zp[i] + (float)zp[i + 1]) * w;
      cs += w;
      if (cs <= xT) { j = i + 1; csj = cs; U += bar; }
    }
    const float Vj = (float)zp[j], Vj1 = (float)zp[j + 1], Wj = (float)zp[NBINS + 1 + j];
    const float alpha = (xT - csj) / Wj;
    const float dV = Vj1 - Vj;
    const float yB = ((0.5f * alpha * alpha * dV + alpha * Vj) * Wj + U) / Vtot;
    const float dens = (Vj + alpha * dV) * Wn / Vtot;
    out[(size_t)(r0 + r) * XSTR + PTS + uu] = yB;
    densl[r][uu] = dens;
    out[(size_t)(r0 + r) * XSTR + uu] = x[(size_t)(r0 + r) * XSTR + uu];
  }
  __syncthreads();
  if (t < 32) {
    float p = jacv[t];
    #pragma unroll
    for (int uu = 0; uu < 8; uu++) p *= densl[t][uu];
    out[(size_t)(r0 + t) * XSTR + 16] = p;
  }
}

extern "C" void kernel_launch(void* const* d_in, const int* in_sizes, int n_in,
                              void* d_out, int out_size, void* d_ws, size_t ws_size,
                              hipStream_t stream) {
  (void)n_in; (void)out_size; (void)ws_size;
  const float* x  = (const float*)d_in[0];
  const float* g0 = (const float*)d_in[1];
  const float* b0 = (const float*)d_in[2];
  const float* w1 = (const float*)d_in[3];
  const float* g1 = (const float*)d_in[4];
  const float* b1 = (const float*)d_in[5];
  const float* w2 = (const float*)d_in[6];
  const float* g2 = (const float*)d_in[7];
  const float* b2 = (const float*)d_in[8];
  const float* w3 = (const float*)d_in[9];
  const float* b3 = (const float*)d_in[10];
  float* out = (float*)d_out;
  float* ws  = (float*)d_ws;
  const int B = in_sizes[0] / XSTR;
  const float invB = 1.0f / (float)B;

  hipMemsetAsync(d_ws, 0, WS_STATS_END * sizeof(float), stream);
  k_stats0<<<256, 256, 0, stream>>>(x, ws, B);
  k_pack_w2<<<(16 * 8 * 64 * 8) / 256, 256, 0, stream>>>(w2, ws);
  k_pack_w3<<<(33 * 8 * 64 * 8) / 256, 256, 0, stream>>>(w3, ws);
  k_fin0<<<1, 256, 0, stream>>>(w1, g0, b0, g1, b1, ws, invB);
  k_pack_w1<<<(16 * 64 * 8) / 256, 256, 0, stream>>>(w1, ws);
  k_stats2<<<512, 512, 0, stream>>>(x, ws, B);
  k_fin2<<<1, 256, 0, stream>>>(g2, b2, ws, invB);
  k_final<<<B / 32, 512, 0, stream>>>(x, b3, ws, out, B);
}

// Round 6
// 173.336 us; speedup vs baseline: 8.7374x; 1.1846x over previous
//
#include <hip/hip_runtime.h>
#include <math.h>

#define PTS   8
#define HID   256
#define OUTD  520
#define NBINS 32
#define XSTR  17
#define BN_EPS 1e-5f
#define LOG2E 1.44269504088896f
#define WZOFF 20480   // byte offset of W zone in LDS (V zone = 5 chunks * 4096B)

typedef short bfrag __attribute__((ext_vector_type(8)));   // 8 bf16 (4 VGPRs)
typedef float f32x4 __attribute__((ext_vector_type(4)));
typedef _Float16 h16x8 __attribute__((ext_vector_type(8)));

union BF8 { bfrag v; ushort u[8]; };

__device__ __forceinline__ ushort f2bf(float f) {          // RNE float->bf16
  uint u = __float_as_uint(f);
  return (ushort)((u + 0x7FFFu + ((u >> 16) & 1u)) >> 16);
}

__device__ __forceinline__ float fexp2(float x) { return __builtin_exp2f(x); }

#define MFMA(a, b, c) __builtin_amdgcn_mfma_f32_16x16x32_bf16((a), (b), (c), 0, 0, 0)

#define WREDUCE(a) { a += __shfl_xor(a,1); a += __shfl_xor(a,2); a += __shfl_xor(a,4); \
                     a += __shfl_xor(a,8); a += __shfl_xor(a,16); a += __shfl_xor(a,32); }

// ---- workspace float offsets ----
#define WS_SC0    0      // 8
#define WS_BI0    8      // 8
#define WS_SC1    16     // 256
#define WS_B1F    272    // 256
#define WS_SC2    528    // 256
#define WS_BI2    784    // 256
#define NC0       64
#define WS_P0     1040   // 64 copies x 44
#define NC2       32
#define WS_P2     3856   // 32 copies x 512 (sum[256], ss[256])
#define WS_STATS_END 20240
#define WS_W1B    20240  // 8192 ushorts
#define WS_W2B    24336  // 65536 ushorts
#define WS_W3B    57104  // 135168 ushorts

// ========== stats0: first + second (upper-tri) moments of xA ==========
__global__ __launch_bounds__(256) void k_stats0(const float* __restrict__ x,
                                                float* __restrict__ ws, int B) {
  float s[8], m[36];
  #pragma unroll
  for (int i = 0; i < 8; i++) s[i] = 0.f;
  #pragma unroll
  for (int k = 0; k < 36; k++) m[k] = 0.f;
  const int stride = gridDim.x * blockDim.x;
  for (int r = blockIdx.x * blockDim.x + threadIdx.x; r < B; r += stride) {
    const float* xr = x + (size_t)r * XSTR;
    float v[8];
    #pragma unroll
    for (int c = 0; c < 8; c++) v[c] = xr[c];
    int tri = 0;
    #pragma unroll
    for (int i = 0; i < 8; i++) {
      s[i] += v[i];
      #pragma unroll
      for (int j = i; j < 8; j++) { m[tri] += v[i] * v[j]; tri++; }
    }
  }
  #pragma unroll
  for (int i = 0; i < 8; i++) WREDUCE(s[i]);
  #pragma unroll
  for (int k = 0; k < 36; k++) WREDUCE(m[k]);
  const int wv = threadIdx.x >> 6;
  if ((threadIdx.x & 63) == 0) {
    float* base = ws + WS_P0 + (size_t)((blockIdx.x * 4 + wv) & (NC0 - 1)) * 44;
    #pragma unroll
    for (int i = 0; i < 8; i++) atomicAdd(&base[i], s[i]);
    #pragma unroll
    for (int k = 0; k < 36; k++) atomicAdd(&base[8 + k], m[k]);
  }
}

// ====== fin0: reduce copies; bn0 params + ANALYTIC bn1 stats + fused bias ======
__global__ void k_fin0(const float* __restrict__ w1, const float* __restrict__ g0,
                       const float* __restrict__ b0, const float* __restrict__ g1,
                       const float* __restrict__ b1, float* __restrict__ ws, float invB) {
  __shared__ float ssum[8], ssxx[8][8];
  __shared__ float smx[8], ssc[8], sbi[8], sma[8], scov[8][8];
  const int t = threadIdx.x;
  if (t < 44) {
    float v = 0.f;
    #pragma unroll 8
    for (int c = 0; c < NC0; c++) v += ws[WS_P0 + c * 44 + t];
    if (t < 8) ssum[t] = v;
    else {
      int k = t - 8, i = 0;
      while (k >= 8 - i) { k -= 8 - i; i++; }
      int j = i + k;
      ssxx[i][j] = v; ssxx[j][i] = v;
    }
  }
  __syncthreads();
  if (t < 8) {
    float mx  = ssum[t] * invB;
    float ex2 = ssxx[t][t] * invB;
    float var = ex2 - mx * mx;
    float sc  = g0[t] * rsqrtf(var + BN_EPS);
    float bi  = b0[t] - mx * sc;
    ws[WS_SC0 + t] = sc; ws[WS_BI0 + t] = bi;
    smx[t] = mx; ssc[t] = sc; sbi[t] = bi; sma[t] = sc * mx + bi;
  }
  __syncthreads();
  if (t < 64) {
    int i = t >> 3, j = t & 7;
    float e = ssc[i] * ssc[j] * (ssxx[i][j] * invB)
            + ssc[i] * smx[i] * sbi[j] + sbi[i] * ssc[j] * smx[j] + sbi[i] * sbi[j];
    scov[i][j] = e - sma[i] * sma[j];
  }
  __syncthreads();
  float wc[8];
  float m1 = 0.f, bvec = 0.f;
  #pragma unroll
  for (int k = 0; k < 8; k++) {
    wc[k] = w1[k * HID + t];
    m1   += sma[k] * wc[k];
    bvec += sbi[k] * wc[k];
  }
  float var1 = 0.f;
  #pragma unroll
  for (int i = 0; i < 8; i++)
    #pragma unroll
    for (int j = 0; j < 8; j++) var1 += wc[i] * wc[j] * scov[i][j];
  float sc1 = g1[t] * rsqrtf(var1 + BN_EPS);
  float bi1 = b1[t] - m1 * sc1;
  ws[WS_SC1 + t] = sc1;
  ws[WS_B1F + t] = bvec * sc1 + bi1;
}

// ================= weight fragment packing (bf16) =================
__global__ void k_pack_w1(const float* __restrict__ w1, float* __restrict__ ws) {
  int idx = blockIdx.x * blockDim.x + threadIdx.x;
  if (idx >= 16 * 64 * 8) return;
  int i = idx & 7, l = (idx >> 3) & 63, n = idx >> 9;
  int k = (l >> 4) * 8 + i, col = n * 16 + (l & 15);
  float v = (k < 8) ? ws[WS_SC0 + k] * w1[k * HID + col] * ws[WS_SC1 + col] : 0.f;
  ((ushort*)(ws + WS_W1B))[idx] = f2bf(v);
}

__global__ void k_pack_w2(const float* __restrict__ w2, float* __restrict__ ws) {
  int idx = blockIdx.x * blockDim.x + threadIdx.x;
  if (idx >= 16 * 8 * 64 * 8) return;
  int i = idx & 7, l = (idx >> 3) & 63, s = (idx >> 9) & 7, n = idx >> 12;
  int k = s * 32 + (l >> 4) * 8 + i, col = n * 16 + (l & 15);
  ((ushort*)(ws + WS_W2B))[idx] = f2bf(w2[k * HID + col]);
}

// w3 packed pre-scaled by log2(e) so layer3's exp is a bare v_exp_f32
__global__ void k_pack_w3(const float* __restrict__ w3, float* __restrict__ ws) {
  int idx = blockIdx.x * blockDim.x + threadIdx.x;
  if (idx >= 33 * 8 * 64 * 8) return;
  int i = idx & 7, l = (idx >> 3) & 63, s = (idx >> 9) & 7, n = idx >> 12;
  int k = s * 32 + (l >> 4) * 8 + i, col = n * 16 + (l & 15);
  float v = (col < OUTD) ? w3[(size_t)k * OUTD + col] * LOG2E : 0.f;
  ((ushort*)(ws + WS_W3B))[idx] = f2bf(v);
}

// ================= stats2: bn2 moments via MFMA h2_pre =================
__global__ __launch_bounds__(512) void k_stats2(const float* __restrict__ x,
                                                float* __restrict__ ws, int B) {
  __shared__ ushort hb[2 * 16 * 256];
  const ushort* w1b = (const ushort*)(ws + WS_W1B);
  const ushort* w2b = (const ushort*)(ws + WS_W2B);
  const int t = threadIdx.x, wv = t >> 6, l = t & 63, lr = l & 15, g = l >> 4;
  float sacc[2] = {0.f, 0.f}, ssacc[2] = {0.f, 0.f};
  const int ntiles = B / 32;
  for (int tile = blockIdx.x; tile < ntiles; tile += gridDim.x) {
    const int r0 = tile * 32;
    BF8 ax[2];
    #pragma unroll
    for (int mt = 0; mt < 2; mt++) {
      if (l < 16) {
        const float* xr = x + (size_t)(r0 + mt * 16 + lr) * XSTR;
        #pragma unroll
        for (int i2 = 0; i2 < 8; i2++) ax[mt].u[i2] = f2bf(xr[i2]);
      } else {
        #pragma unroll
        for (int i2 = 0; i2 < 8; i2++) ax[mt].u[i2] = 0;
      }
    }
    // layer1 -> h1 (LDS, swizzled)
    #pragma unroll
    for (int j = 0; j < 2; j++) {
      int n = wv * 2 + j;
      BF8 bw; bw.v = *(const bfrag*)(w1b + ((size_t)n * 64 + l) * 8);
      int col = n * 16 + lr;
      float b1fv = ws[WS_B1F + col];
      f32x4 cini = {b1fv, b1fv, b1fv, b1fv};
      #pragma unroll
      for (int mt = 0; mt < 2; mt++) {
        f32x4 d = MFMA(ax[mt].v, bw.v, cini);
        #pragma unroll
        for (int r = 0; r < 4; r++) {
          int row = 4 * g + r;
          float h = fmaxf(d[r], 0.f);
          int byte = ((mt * 16 + row) * 256) * 2 + ((col * 2) ^ ((row & 7) << 4));
          *(ushort*)((char*)hb + byte) = f2bf(h);
        }
      }
    }
    __syncthreads();
    BF8 a2[2][8];
    #pragma unroll
    for (int mt = 0; mt < 2; mt++)
      #pragma unroll
      for (int s = 0; s < 8; s++) {
        int byte = ((mt * 16 + lr) * 256) * 2 + ((s * 64 + g * 16) ^ ((lr & 7) << 4));
        a2[mt][s].v = *(const bfrag*)((const char*)hb + byte);
      }
    __syncthreads();
    // layer2 h2_pre, accumulate moments
    #pragma unroll
    for (int j = 0; j < 2; j++) {
      int n = wv * 2 + j;
      f32x4 acc0 = {0.f, 0.f, 0.f, 0.f}, acc1 = {0.f, 0.f, 0.f, 0.f};
      #pragma unroll
      for (int s = 0; s < 8; s++) {
        BF8 bw; bw.v = *(const bfrag*)(w2b + (((size_t)n * 8 + s) * 64 + l) * 8);
        acc0 = MFMA(a2[0][s].v, bw.v, acc0);
        acc1 = MFMA(a2[1][s].v, bw.v, acc1);
      }
      float ls = 0.f, lss = 0.f;
      #pragma unroll
      for (int r = 0; r < 4; r++) {
        ls  += acc0[r] + acc1[r];
        lss += acc0[r] * acc0[r] + acc1[r] * acc1[r];
      }
      sacc[j] += ls; ssacc[j] += lss;
    }
  }
  #pragma unroll
  for (int j = 0; j < 2; j++) {
    float a = sacc[j], b = ssacc[j];
    a += __shfl_xor(a, 16); a += __shfl_xor(a, 32);
    b += __shfl_xor(b, 16); b += __shfl_xor(b, 32);
    if (g == 0) {
      int col = (wv * 2 + j) * 16 + lr;
      float* base = ws + WS_P2 + (size_t)(blockIdx.x & (NC2 - 1)) * 512;
      atomicAdd(&base[col], a);
      atomicAdd(&base[256 + col], b);
    }
  }
}

__global__ void k_fin2(const float* __restrict__ g2, const float* __restrict__ b2,
                       float* __restrict__ ws, float invB) {
  int t = threadIdx.x;
  float s = 0.f, ss = 0.f;
  #pragma unroll 8
  for (int c = 0; c < NC2; c++) {
    s  += ws[WS_P2 + c * 512 + t];
    ss += ws[WS_P2 + c * 512 + 256 + t];
  }
  float m   = s * invB;
  float var = ss * invB - m * m;
  float sc  = g2[t] * rsqrtf(var + BN_EPS);
  ws[WS_SC2 + t] = sc;
  ws[WS_BI2 + t] = b2[t] - m * sc;
}

// ================= final: full fused pipeline =================
// LDS layout (36864 B), phases alias:
//   [0, 16384)      : hb      — h1/h2 bf16 staging (swizzled), dead after a3 reads
//   [0, 20480)      : V zone  — exp(Z) V-part, chunk-major: byte = chunk*4096 + ru*16 + off*2
//   [20480, 36864)  : W zone  — exp(Z) W-part, same scheme
__global__ __launch_bounds__(512, 4) void k_final(const float* __restrict__ x,
                                                  const float* __restrict__ b3,
                                                  const float* __restrict__ ws,
                                                  float* __restrict__ out, int B) {
  __shared__ __align__(16) char lds[36864];
  const ushort* w1b = (const ushort*)(ws + WS_W1B);
  const ushort* w2b = (const ushort*)(ws + WS_W2B);
  const ushort* w3b = (const ushort*)(ws + WS_W3B);
  const int t = threadIdx.x, wv = t >> 6, l = t & 63, lr = l & 15, g = l >> 4;
  const int r0 = blockIdx.x * 32;

  // waves 4-7: xA passthrough (independent of everything)
  if (t >= 256) {
    int tt = t - 256;
    int r = tt >> 3, c = tt & 7;
    out[(size_t)(r0 + r) * XSTR + c] = x[(size_t)(r0 + r) * XSTR + c];
  }

  BF8 ax[2];
  #pragma unroll
  for (int mt = 0; mt < 2; mt++) {
    if (l < 16) {
      const float* xr = x + (size_t)(r0 + mt * 16 + lr) * XSTR;
      #pragma unroll
      for (int i2 = 0; i2 < 8; i2++) ax[mt].u[i2] = f2bf(xr[i2]);
    } else {
      #pragma unroll
      for (int i2 = 0; i2 < 8; i2++) ax[mt].u[i2] = 0;
    }
  }
  // ---- layer1 -> h1 ----
  #pragma unroll
  for (int j = 0; j < 2; j++) {
    int n = wv * 2 + j;
    BF8 bw; bw.v = *(const bfrag*)(w1b + ((size_t)n * 64 + l) * 8);
    int col = n * 16 + lr;
    float b1fv = ws[WS_B1F + col];
    f32x4 cini = {b1fv, b1fv, b1fv, b1fv};
    #pragma unroll
    for (int mt = 0; mt < 2; mt++) {
      f32x4 d = MFMA(ax[mt].v, bw.v, cini);
      #pragma unroll
      for (int r = 0; r < 4; r++) {
        int row = 4 * g + r;
        float h = fmaxf(d[r], 0.f);
        int byte = ((mt * 16 + row) * 256) * 2 + ((col * 2) ^ ((row & 7) << 4));
        *(ushort*)(lds + byte) = f2bf(h);
      }
    }
  }
  __syncthreads();
  BF8 a2[2][8];
  #pragma unroll
  for (int mt = 0; mt < 2; mt++)
    #pragma unroll
    for (int s = 0; s < 8; s++) {
      int byte = ((mt * 16 + lr) * 256) * 2 + ((s * 64 + g * 16) ^ ((lr & 7) << 4));
      a2[mt][s].v = *(const bfrag*)(lds + byte);
    }
  __syncthreads();
  // ---- layer2 -> h2 ----
  #pragma unroll
  for (int j = 0; j < 2; j++) {
    int n = wv * 2 + j;
    f32x4 acc0 = {0.f, 0.f, 0.f, 0.f}, acc1 = {0.f, 0.f, 0.f, 0.f};
    #pragma unroll
    for (int s = 0; s < 8; s++) {
      BF8 bw; bw.v = *(const bfrag*)(w2b + (((size_t)n * 8 + s) * 64 + l) * 8);
      acc0 = MFMA(a2[0][s].v, bw.v, acc0);
      acc1 = MFMA(a2[1][s].v, bw.v, acc1);
    }
    int col = n * 16 + lr;
    float sc = ws[WS_SC2 + col], bi = ws[WS_BI2 + col];
    #pragma unroll
    for (int r = 0; r < 4; r++) {
      int row = 4 * g + r;
      float h0 = fmaxf(acc0[r] * sc + bi, 0.f);
      float h1v = fmaxf(acc1[r] * sc + bi, 0.f);
      int sw = (col * 2) ^ ((row & 7) << 4);
      *(ushort*)(lds + ((0 * 16 + row) * 256) * 2 + sw) = f2bf(h0);
      *(ushort*)(lds + ((1 * 16 + row) * 256) * 2 + sw) = f2bf(h1v);
    }
  }
  __syncthreads();
  BF8 a3[2][8];
  #pragma unroll
  for (int mt = 0; mt < 2; mt++)
    #pragma unroll
    for (int s = 0; s < 8; s++) {
      int byte = ((mt * 16 + lr) * 256) * 2 + ((s * 64 + g * 16) ^ ((lr & 7) << 4));
      a3[mt][s].v = *(const bfrag*)(lds + byte);
    }
  __syncthreads();   // all reads done; V/W zones may now overwrite hb
  // ---- layer3: exp(h2 @ w3*log2e + b3*log2e) as fp16 into split V/W zones ----
  #pragma unroll
  for (int k = 0; k < 5; k++) {
    int n = wv + 8 * k;
    if (n < 33) {
      int col = n * 16 + lr;
      bool valid = (col < OUTD);
      float bias = valid ? b3[col] * LOG2E : 0.f;
      f32x4 acc0 = {bias, bias, bias, bias}, acc1 = {bias, bias, bias, bias};
      #pragma unroll
      for (int s = 0; s < 8; s++) {
        BF8 bw; bw.v = *(const bfrag*)(w3b + (((size_t)n * 8 + s) * 64 + l) * 8);
        acc0 = MFMA(a3[0][s].v, bw.v, acc0);
        acc1 = MFMA(a3[1][s].v, bw.v, acc1);
      }
      if (valid) {
        int uu = (col * 1009) >> 16;          // col / 65
        int q  = col - uu * 65;               // col % 65
        bool isv = (q < 33);
        int qz = isv ? q : (q - 33);
        int bb = (isv ? 0 : WZOFF) + (qz >> 3) * 4096 + (qz & 7) * 2 + uu * 16;
        #pragma unroll
        for (int r = 0; r < 4; r++) {
          int row = 4 * g + r;
          *(_Float16*)(lds + bb + row * 128)        = (_Float16)fexp2(acc0[r]);
          *(_Float16*)(lds + bb + (16 + row) * 128) = (_Float16)fexp2(acc1[r]);
        }
      }
    }
  }
  __syncthreads();
  // ---- spline: waves 0-3, all operands in registers ----
  if (t < 256) {
    const int r = t >> 3, uu2 = t & 7;
    const float xB   = fminf(x[(size_t)(r0 + r) * XSTR + PTS + uu2], 1.f - 1e-6f);
    const float xjac = x[(size_t)(r0 + r) * XSTR + 16];
    h16x8 vv[5], wwv[4];
    #pragma unroll
    for (int k = 0; k < 5; k++) vv[k] = *(const h16x8*)(lds + (k * 256 + t) * 16);
    #pragma unroll
    for (int k = 0; k < 4; k++) wwv[k] = *(const h16x8*)(lds + WZOFF + (k * 256 + t) * 16);
    #define VF(i) ((float)vv[(i) >> 3][(i) & 7])
    #define WF(i) ((float)wwv[(i) >> 3][(i) & 7])
    float Wn = 0.f, Vtot = 0.f;
    {
      float vprev = VF(0);
      #pragma unroll
      for (int i = 0; i < NBINS; i++) {
        float v1 = VF(i + 1);
        float w  = WF(i);
        Wn += w; Vtot += 0.5f * (vprev + v1) * w; vprev = v1;
      }
    }
    const float xT = xB * Wn;
    float cs = 0.f, csj = 0.f, U = 0.f;
    float Vj = VF(0), Vj1 = VF(1), Wj = WF(0);
    #pragma unroll
    for (int i = 0; i < NBINS - 1; i++) {   // i=31 provably fails cs<=xT (xB<1)
      float w = WF(i);
      float bar = 0.5f * (VF(i) + VF(i + 1)) * w;
      cs += w;
      if (cs <= xT) {
        csj = cs; U += bar;
        Vj = VF(i + 1); Vj1 = VF(i + 2); Wj = WF(i + 1);
      }
    }
    const float alpha = (xT - csj) / Wj;
    const float dV = Vj1 - Vj;
    const float yB = ((0.5f * alpha * alpha * dV + alpha * Vj) * Wj + U) / Vtot;
    const float dens = (Vj + alpha * dV) * Wn / Vtot;
    out[(size_t)(r0 + r) * XSTR + PTS + uu2] = yB;
    float p = dens;
    p *= __shfl_xor(p, 1); p *= __shfl_xor(p, 2); p *= __shfl_xor(p, 4);
    if (uu2 == 0) out[(size_t)(r0 + r) * XSTR + 16] = xjac * p;
    #undef VF
    #undef WF
  }
}

extern "C" void kernel_launch(void* const* d_in, const int* in_sizes, int n_in,
                              void* d_out, int out_size, void* d_ws, size_t ws_size,
                              hipStream_t stream) {
  (void)n_in; (void)out_size; (void)ws_size;
  const float* x  = (const float*)d_in[0];
  const float* g0 = (const float*)d_in[1];
  const float* b0 = (const float*)d_in[2];
  const float* w1 = (const float*)d_in[3];
  const float* g1 = (const float*)d_in[4];
  const float* b1 = (const float*)d_in[5];
  const float* w2 = (const float*)d_in[6];
  const float* g2 = (const float*)d_in[7];
  const float* b2 = (const float*)d_in[8];
  const float* w3 = (const float*)d_in[9];
  const float* b3 = (const float*)d_in[10];
  float* out = (float*)d_out;
  float* ws  = (float*)d_ws;
  const int B = in_sizes[0] / XSTR;
  const float invB = 1.0f / (float)B;

  hipMemsetAsync(d_ws, 0, WS_STATS_END * sizeof(float), stream);
  k_stats0<<<256, 256, 0, stream>>>(x, ws, B);
  k_pack_w2<<<(16 * 8 * 64 * 8) / 256, 256, 0, stream>>>(w2, ws);
  k_pack_w3<<<(33 * 8 * 64 * 8) / 256, 256, 0, stream>>>(w3, ws);
  k_fin0<<<1, 256, 0, stream>>>(w1, g0, b0, g1, b1, ws, invB);
  k_pack_w1<<<(16 * 64 * 8) / 256, 256, 0, stream>>>(w1, ws);
  k_stats2<<<512, 512, 0, stream>>>(x, ws, B);
  k_fin2<<<1, 256, 0, stream>>>(g2, b2, ws, invB);
  k_final<<<B / 32, 512, 0, stream>>>(x, b3, ws, out, B);
}